// Round 1
// baseline (2832.654 us; speedup 1.0000x reference)
//
#include <hip/hip_runtime.h>
#include <hip/hip_bf16.h>

#define N1 (1u << 20)   // B*NH*HW = 16*64*1024

static __device__ __forceinline__ float sigm(float x){ return 1.f/(1.f + __expf(-x)); }
static __device__ __forceinline__ float tanh_(float x){ return 1.f - 2.f/(__expf(2.f*x) + 1.f); }

static __device__ __forceinline__ void red_atomic2(float s, float q, float* d, int b, int t){
  #pragma unroll
  for (int m = 32; m; m >>= 1){ s += __shfl_xor(s, m); q += __shfl_xor(q, m); }
  if ((t & 63) == 0){ atomicAdd(&d[b*2], s); atomicAdd(&d[b*2+1], q); }
}

__global__ void k_zero(float* __restrict__ p){ p[threadIdx.x] = 0.f; }

// ---------------------------------------------------------------------------
// Direct 5x5 SAME conv, NCHW, 32x32 images. COB output channels per block.
// Optional: LayerNorm applied to the INPUT while staging (stats+g+b),
// optional bias on output, optional sum/sumsq stats accumulation on OUTPUT.
// ---------------------------------------------------------------------------
template<int COB>
__global__ __launch_bounds__(256) void k_conv5(
    const float* __restrict__ in, int Cin,
    const float* __restrict__ wgt, const float* __restrict__ bias,
    float* __restrict__ out, int Cout,
    float* __restrict__ out_stats,
    const float* __restrict__ in_stats, float in_invN,
    const float* __restrict__ in_g, const float* __restrict__ in_b)
{
  const int b   = blockIdx.y;
  const int co0 = blockIdx.x * COB;
  const int t   = threadIdx.x;
  __shared__ __align__(16) float plane[36*36];
  __shared__ __align__(16) float wsh[25][COB];
  float acc[COB][4];
  #pragma unroll
  for (int j = 0; j < COB; ++j){ acc[j][0]=0.f; acc[j][1]=0.f; acc[j][2]=0.f; acc[j][3]=0.f; }

  float mean = 0.f, rstd = 0.f;
  if (in_stats){
    float s0 = in_stats[b*2], s1 = in_stats[b*2+1];
    mean = s0 * in_invN;
    float var = s1 * in_invN - mean*mean;
    rstd = rsqrtf(var + 1e-5f);
  }
  const int px0 = t & 31, py0 = t >> 5;

  for (int ci = 0; ci < Cin; ++ci){
    __syncthreads();
    const float* ip = in + ((size_t)(b*Cin + ci) << 10);
    const float* gp = in_g ? in_g + ((size_t)ci << 10) : nullptr;
    const float* bp = in_b ? in_b + ((size_t)ci << 10) : nullptr;
    for (int i = t; i < 1296; i += 256){
      int py = i / 36, px = i - py*36;
      int y = py - 2, x = px - 2;
      float v = 0.f;
      if ((unsigned)y < 32u && (unsigned)x < 32u){
        v = ip[(y << 5) + x];
        if (gp) v = (v - mean)*rstd*gp[(y << 5) + x] + bp[(y << 5) + x];
      }
      plane[i] = v;
    }
    if (t < 25*COB){
      int j = t / 25, tap = t - j*25;
      wsh[tap][j] = wgt[((size_t)(co0 + j)*Cin + ci)*25 + tap];
    }
    __syncthreads();
    #pragma unroll
    for (int dy = 0; dy < 5; ++dy){
      #pragma unroll
      for (int dx = 0; dx < 5; ++dx){
        const int tap = dy*5 + dx;
        float pv[4];
        #pragma unroll
        for (int pi = 0; pi < 4; ++pi) pv[pi] = plane[(py0 + 8*pi + dy)*36 + px0 + dx];
        float wreg[COB];
        *(float4*)&wreg[0] = *(const float4*)&wsh[tap][0];
        if constexpr (COB == 8) *(float4*)&wreg[4] = *(const float4*)&wsh[tap][4];
        #pragma unroll
        for (int j = 0; j < COB; ++j){
          #pragma unroll
          for (int pi = 0; pi < 4; ++pi) acc[j][pi] = fmaf(wreg[j], pv[pi], acc[j][pi]);
        }
      }
    }
  }
  float lsum = 0.f, lsq = 0.f;
  #pragma unroll
  for (int j = 0; j < COB; ++j){
    float bb = bias ? bias[co0 + j] : 0.f;
    float* op = out + ((size_t)(b*Cout + co0 + j) << 10) + t;
    #pragma unroll
    for (int pi = 0; pi < 4; ++pi){
      float v = acc[j][pi] + bb;
      op[pi << 8] = v;
      lsum += v; lsq += v*v;
    }
  }
  if (out_stats) red_atomic2(lsum, lsq, out_stats, b, t);
}

// ---------------------------------------------------------------------------
// Gates: LN-apply x/h/m conv outputs, compute i/f/g (both sets), m_new, o_x+o_h
// ---------------------------------------------------------------------------
__global__ __launch_bounds__(256) void k_gates(
    const float* __restrict__ bufx, const float* __restrict__ bufh, const float* __restrict__ bufm,
    const float* __restrict__ lnxg, const float* __restrict__ lnxb,
    const float* __restrict__ lnhg, const float* __restrict__ lnhb,
    const float* __restrict__ lnmg, const float* __restrict__ lnmb,
    const float* __restrict__ m_t, const float* __restrict__ stats,
    float* __restrict__ ft, float* __restrict__ ig, float* __restrict__ osum,
    float* __restrict__ memo, float* __restrict__ out_m)
{
  const int idx = blockIdx.x*256 + threadIdx.x;
  const int b = idx >> 16, rem = idx & 65535;
  const int c = rem >> 10, p = rem & 1023;

  float mx = stats[b*2]      * (1.f/458752.f);
  float vx = stats[b*2+1]    * (1.f/458752.f) - mx*mx;  float rx = rsqrtf(vx + 1e-5f);
  float mh = stats[32+b*2]   * (1.f/262144.f);
  float vh = stats[32+b*2+1] * (1.f/262144.f) - mh*mh;  float rh = rsqrtf(vh + 1e-5f);
  float mm = stats[64+b*2]   * (1.f/196608.f);
  float vm = stats[64+b*2+1] * (1.f/196608.f) - mm*mm;  float rm = rsqrtf(vm + 1e-5f);

  auto LX = [&](int k){
    size_t ch = (size_t)k*64 + c; size_t gi = ((size_t)b*448 + ch)*1024 + p; size_t li = ch*1024 + p;
    return (bufx[gi] - mx)*rx*lnxg[li] + lnxb[li]; };
  auto LH = [&](int k){
    size_t ch = (size_t)k*64 + c; size_t gi = ((size_t)b*256 + ch)*1024 + p; size_t li = ch*1024 + p;
    return (bufh[gi] - mh)*rh*lnhg[li] + lnhb[li]; };
  auto LM = [&](int k){
    size_t ch = (size_t)k*64 + c; size_t gi = ((size_t)b*192 + ch)*1024 + p; size_t li = ch*1024 + p;
    return (bufm[gi] - mm)*rm*lnmg[li] + lnmb[li]; };

  float i_t = sigm(LX(0) + LH(0));
  float f_t = sigm(LX(1) + LH(1) + 1.f);
  float g_t = tanh_(LX(2) + LH(2));
  float i_p = sigm(LX(3) + LM(0));
  float f_p = sigm(LX(4) + LM(1) + 1.f);
  float g_p = tanh_(LX(5) + LM(2));
  float ox = LX(6), oh = LH(3);

  ft[idx]   = f_t;
  ig[idx]   = i_t * g_t;
  osum[idx] = ox + oh;
  float mn = f_p * m_t[idx] + i_p * g_p;
  out_m[idx] = mn;
  memo[((size_t)(b*128 + 64 + c) << 10) + p] = mn;
}

// ---------------------------------------------------------------------------
// Spatial attention, fused single-pass softmax (fixed shift, fp32-safe):
// out[b][c][p] = sum_q softmax_q(sum_c' ft[c'][p]*kv[q][c']) * kv[q][c]
// One block: 64 pixel rows, full 64-channel width. sp_raw = c_t + out; stats.
// ---------------------------------------------------------------------------
__global__ __launch_bounds__(256) void k_spat(
    const float* __restrict__ ft, const float* __restrict__ chist,
    const float* __restrict__ c_t,
    float* __restrict__ sp_raw, float* __restrict__ stats)
{
  const int p0 = blockIdx.x << 6;
  const int b  = blockIdx.y;
  const int t  = threadIdx.x;
  const int tr = t & 15, tc = t >> 4;
  __shared__ __align__(16) float Qs[64][68];
  __shared__ __align__(16) float Ks[64][68];
  __shared__ __align__(16) float Es[64][68];
  float num[4][4] = {};
  float den[4]    = {};
  {
    const int r = t & 63, c0 = t >> 6;
    const float* qp = ft + ((size_t)b << 16) + p0 + r;
    #pragma unroll
    for (int c = c0; c < 64; c += 4) Qs[r][c] = qp[(size_t)c << 10];
  }
  __syncthreads();
  for (int chunk = 0; chunk < 64; ++chunk){
    const int l  = chunk >> 4;
    const int pk = (chunk & 15) << 6;
    {
      const int r = t & 63, c0 = t >> 6;
      const float* kp = chist + (((size_t)(b*4 + l)) << 16) + pk + r;
      #pragma unroll
      for (int c = c0; c < 64; c += 4) Ks[r][c] = kp[(size_t)c << 10];
    }
    __syncthreads();
    float s[4][4] = {};
    #pragma unroll 4
    for (int c = 0; c < 64; c += 4){
      float qv[4][4], kv[4][4];
      #pragma unroll
      for (int i = 0; i < 4; ++i) *(float4*)qv[i] = *(const float4*)&Qs[4*tr+i][c];
      #pragma unroll
      for (int j = 0; j < 4; ++j) *(float4*)kv[j] = *(const float4*)&Ks[4*tc+j][c];
      #pragma unroll
      for (int i = 0; i < 4; ++i)
        #pragma unroll
        for (int j = 0; j < 4; ++j)
          #pragma unroll
          for (int k = 0; k < 4; ++k)
            s[i][j] = fmaf(qv[i][k], kv[j][k], s[i][j]);
    }
    #pragma unroll
    for (int i = 0; i < 4; ++i)
      #pragma unroll
      for (int j = 0; j < 4; ++j){
        float e = __expf(s[i][j] - 12.f);
        Es[4*tr+i][4*tc+j] = e;
        den[i] += e;
      }
    __syncthreads();
    #pragma unroll 4
    for (int q = 0; q < 64; q += 4){
      float ev[4][4], kv[4][4];
      #pragma unroll
      for (int i = 0; i < 4; ++i) *(float4*)ev[i] = *(const float4*)&Es[4*tr+i][q];
      #pragma unroll
      for (int j = 0; j < 4; ++j) *(float4*)kv[j] = *(const float4*)&Ks[q+j][4*tc];
      #pragma unroll
      for (int i = 0; i < 4; ++i)
        #pragma unroll
        for (int cj = 0; cj < 4; ++cj)
          #pragma unroll
          for (int j = 0; j < 4; ++j)
            num[i][cj] = fmaf(ev[i][j], kv[j][cj], num[i][cj]);
    }
    __syncthreads();
  }
  // reduce den across the 16 tc groups (reuse Es)
  #pragma unroll
  for (int i = 0; i < 4; ++i) Es[4*tr+i][tc] = den[i];
  __syncthreads();
  float lsum = 0.f, lsq = 0.f;
  #pragma unroll
  for (int i = 0; i < 4; ++i){
    float d = 0.f;
    #pragma unroll
    for (int k = 0; k < 16; ++k) d += Es[4*tr+i][k];
    float inv = 1.f / d;
    #pragma unroll
    for (int j = 0; j < 4; ++j){
      const int c = 4*tc + j, r = 4*tr + i;
      size_t gi = ((size_t)b << 16) + ((size_t)c << 10) + p0 + r;
      float v = c_t[gi] + num[i][j]*inv;
      sp_raw[gi] = v;
      lsum += v; lsq += v*v;
    }
  }
  red_atomic2(lsum, lsq, stats, b, t);
}

// ---------------------------------------------------------------------------
// Channel attention: logits GEMM, wave softmax, AV GEMM
// ---------------------------------------------------------------------------
__global__ __launch_bounds__(256) void k_chlog(
    const float* __restrict__ ft, const float* __restrict__ chist, float* __restrict__ lg)
{
  const int l = blockIdx.x, b = blockIdx.y, t = threadIdx.x;
  const int tc = t & 15, tk = t >> 4;
  __shared__ __align__(16) float Fs[64][68];
  __shared__ __align__(16) float Ks[64][68];
  float acc[4][4] = {};
  for (int pc = 0; pc < 16; ++pc){
    __syncthreads();
    {
      const int j = t & 63, c0 = t >> 6;
      const float* fp = ft + ((size_t)b << 16) + (pc << 6) + j;
      const float* kp = chist + (((size_t)(b*4 + l)) << 16) + (pc << 6) + j;
      #pragma unroll
      for (int c = c0; c < 64; c += 4){ Fs[c][j] = fp[(size_t)c << 10]; Ks[c][j] = kp[(size_t)c << 10]; }
    }
    __syncthreads();
    #pragma unroll 4
    for (int p = 0; p < 64; p += 4){
      float fv[4][4], kv[4][4];
      #pragma unroll
      for (int i = 0; i < 4; ++i) *(float4*)fv[i] = *(const float4*)&Fs[4*tc+i][p];
      #pragma unroll
      for (int j = 0; j < 4; ++j) *(float4*)kv[j] = *(const float4*)&Ks[4*tk+j][p];
      #pragma unroll
      for (int i = 0; i < 4; ++i)
        #pragma unroll
        for (int j = 0; j < 4; ++j)
          #pragma unroll
          for (int k = 0; k < 4; ++k)
            acc[i][j] = fmaf(fv[i][k], kv[j][k], acc[i][j]);
    }
  }
  #pragma unroll
  for (int i = 0; i < 4; ++i)
    #pragma unroll
    for (int j = 0; j < 4; ++j)
      lg[((size_t)(b*64 + 4*tc + i) << 8) + (l << 6) + 4*tk + j] = acc[i][j];
}

__global__ __launch_bounds__(256) void k_chsm(float* __restrict__ a)
{
  const int row  = blockIdx.x*4 + (threadIdx.x >> 6);
  const int lane = threadIdx.x & 63;
  float* rp = a + ((size_t)row << 8);
  float v0 = rp[lane], v1 = rp[lane+64], v2 = rp[lane+128], v3 = rp[lane+192];
  float mx = fmaxf(fmaxf(v0, v1), fmaxf(v2, v3));
  #pragma unroll
  for (int m = 32; m; m >>= 1) mx = fmaxf(mx, __shfl_xor(mx, m));
  v0 = __expf(v0 - mx); v1 = __expf(v1 - mx); v2 = __expf(v2 - mx); v3 = __expf(v3 - mx);
  float s = v0 + v1 + v2 + v3;
  #pragma unroll
  for (int m = 32; m; m >>= 1) s += __shfl_xor(s, m);
  float inv = 1.f / s;
  rp[lane] = v0*inv; rp[lane+64] = v1*inv; rp[lane+128] = v2*inv; rp[lane+192] = v3*inv;
}

__global__ __launch_bounds__(256) void k_chout(
    const float* __restrict__ a, const float* __restrict__ chist,
    const float* __restrict__ c_t, float* __restrict__ ch_raw, float* __restrict__ stats)
{
  const int p0 = blockIdx.x << 6, b = blockIdx.y, t = threadIdx.x;
  const int tc = t & 15, tp = t >> 4;
  __shared__ __align__(16) float As[64][68];
  __shared__ __align__(16) float Ks[64][68];
  float acc[4][4] = {};
  for (int h = 0; h < 4; ++h){
    __syncthreads();
    {
      const int j = t & 63, c0 = t >> 6;
      const float* ap = a + ((size_t)b << 14) + (h << 6) + j;
      #pragma unroll
      for (int c = c0; c < 64; c += 4) As[j][c] = ap[(size_t)c << 8];
      const int p = t & 63, j0 = t >> 6;
      const float* kp = chist + (((size_t)(b*4 + h)) << 16) + p0 + p;
      #pragma unroll
      for (int jj = j0; jj < 64; jj += 4) Ks[jj][p] = kp[(size_t)jj << 10];
    }
    __syncthreads();
    #pragma unroll 4
    for (int k = 0; k < 64; k += 4){
      float av[4][4], kv[4][4];
      #pragma unroll
      for (int j = 0; j < 4; ++j){ *(float4*)av[j] = *(const float4*)&As[k+j][4*tc];
                                   *(float4*)kv[j] = *(const float4*)&Ks[k+j][4*tp]; }
      #pragma unroll
      for (int ci = 0; ci < 4; ++ci)
        #pragma unroll
        for (int pi = 0; pi < 4; ++pi)
          #pragma unroll
          for (int j = 0; j < 4; ++j)
            acc[ci][pi] = fmaf(av[j][ci], kv[j][pi], acc[ci][pi]);
    }
  }
  float lsum = 0.f, lsq = 0.f;
  #pragma unroll
  for (int ci = 0; ci < 4; ++ci)
    #pragma unroll
    for (int pi = 0; pi < 4; ++pi){
      size_t gi = ((size_t)b << 16) + ((size_t)(4*tc + ci) << 10) + p0 + 4*tp + pi;
      float v = c_t[gi] + acc[ci][pi];
      ch_raw[gi] = v;
      lsum += v; lsq += v*v;
    }
  red_atomic2(lsum, lsq, stats, b, t);
}

// ---------------------------------------------------------------------------
// LN+relu both attention branches, 1x1 convs sa_w2/ca_w2, sum, 1x1 attn_w,
// c_new = attn + i_t*g_t  -> d_out (c slot) and memo lower half
// ---------------------------------------------------------------------------
__global__ __launch_bounds__(256) void k_attnfinal(
    const float* __restrict__ samid, const float* __restrict__ camid,
    const float* __restrict__ stats_sa, const float* __restrict__ stats_ca,
    const float* __restrict__ salng, const float* __restrict__ salnb,
    const float* __restrict__ calng, const float* __restrict__ calnb,
    const float* __restrict__ wsa2, const float* __restrict__ wca2,
    const float* __restrict__ cab2, const float* __restrict__ wat,
    const float* __restrict__ ig, float* __restrict__ out_c, float* __restrict__ memo)
{
  const int p0 = blockIdx.x << 6, b = blockIdx.y, t = threadIdx.x;
  const int tc = t & 15, tp = t >> 4;
  __shared__ __align__(16) float R[64][68];
  __shared__ __align__(16) float Wl[64][68];
  __shared__ __align__(16) float Ms[64][68];
  const float invN = 1.f/65536.f;
  float acc[4][4] = {};
  #pragma unroll
  for (int pass = 0; pass < 2; ++pass){
    const float* mid = pass ? camid : samid;
    const float* st  = pass ? stats_ca : stats_sa;
    const float* g   = pass ? calng : salng;
    const float* bb  = pass ? calnb : salnb;
    const float* w   = pass ? wca2  : wsa2;
    float mean = st[b*2]*invN;
    float var  = st[b*2+1]*invN - mean*mean;
    float rstd = rsqrtf(var + 1e-5f);
    __syncthreads();
    {
      const int j = t & 63, c0 = t >> 6;
      for (int ci = c0; ci < 64; ci += 4){
        size_t gi = ((size_t)b << 16) + ((size_t)ci << 10) + p0 + j;
        size_t li = ((size_t)ci << 10) + p0 + j;
        float v = (mid[gi] - mean)*rstd*g[li] + bb[li];
        R[ci][j] = fmaxf(v, 0.f);
      }
      const int ci2 = t & 63, c20 = t >> 6;
      for (int c2 = c20; c2 < 64; c2 += 4) Wl[ci2][c2] = w[((size_t)c2 << 6) + ci2];
    }
    __syncthreads();
    for (int ci = 0; ci < 64; ++ci){
      float wv[4], rv[4];
      *(float4*)wv = *(const float4*)&Wl[ci][4*tc];
      *(float4*)rv = *(const float4*)&R[ci][4*tp];
      #pragma unroll
      for (int i = 0; i < 4; ++i)
        #pragma unroll
        for (int j = 0; j < 4; ++j)
          acc[i][j] = fmaf(wv[i], rv[j], acc[i][j]);
    }
  }
  {
    float b2[4];
    #pragma unroll
    for (int i = 0; i < 4; ++i) b2[i] = cab2[4*tc + i];
    #pragma unroll
    for (int i = 0; i < 4; ++i)
      #pragma unroll
      for (int j = 0; j < 4; ++j)
        Ms[4*tc+i][4*tp+j] = acc[i][j] + b2[i];
  }
  __syncthreads();
  {
    const int ci2 = t & 63, c20 = t >> 6;
    for (int c2 = c20; c2 < 64; c2 += 4) Wl[ci2][c2] = wat[((size_t)c2 << 6) + ci2];
  }
  __syncthreads();
  float acc2[4][4] = {};
  for (int c2 = 0; c2 < 64; ++c2){
    float wv[4], mv[4];
    *(float4*)wv = *(const float4*)&Wl[c2][4*tc];
    *(float4*)mv = *(const float4*)&Ms[c2][4*tp];
    #pragma unroll
    for (int i = 0; i < 4; ++i)
      #pragma unroll
      for (int j = 0; j < 4; ++j)
        acc2[i][j] = fmaf(wv[i], mv[j], acc2[i][j]);
  }
  #pragma unroll
  for (int i = 0; i < 4; ++i)
    #pragma unroll
    for (int j = 0; j < 4; ++j){
      size_t gi = ((size_t)b << 16) + ((size_t)(4*tc + i) << 10) + p0 + 4*tp + j;
      float v = acc2[i][j] + ig[gi];
      out_c[gi] = v;
      memo[((size_t)(b*128 + 4*tc + i) << 10) + p0 + 4*tp + j] = v;
    }
}

// ---------------------------------------------------------------------------
// h_new = sigmoid(o_x+o_h + LN_o(conv_o)) * tanh(w_last(1x1) @ mem)
// ---------------------------------------------------------------------------
__global__ __launch_bounds__(256) void k_final(
    const float* __restrict__ memo, const float* __restrict__ wlast,
    const float* __restrict__ bufo, const float* __restrict__ osum,
    const float* __restrict__ stats_o, const float* __restrict__ lnog, const float* __restrict__ lnob,
    float* __restrict__ out_h)
{
  const int p0 = blockIdx.x << 6, b = blockIdx.y, t = threadIdx.x;
  const int tc = t & 15, tp = t >> 4;
  __shared__ __align__(16) float Msh[64][68];
  __shared__ __align__(16) float Wt[64][68];
  float acc[4][4] = {};
  #pragma unroll
  for (int half = 0; half < 2; ++half){
    __syncthreads();
    {
      const int j = t & 63, c0 = t >> 6;
      for (int ci = c0; ci < 64; ci += 4)
        Msh[ci][j] = memo[((size_t)(b*128 + half*64 + ci) << 10) + p0 + j];
      const int ci2 = t & 63, co0 = t >> 6;
      for (int co = co0; co < 64; co += 4) Wt[ci2][co] = wlast[((size_t)co << 7) + half*64 + ci2];
    }
    __syncthreads();
    for (int ci = 0; ci < 64; ++ci){
      float wv[4], mv[4];
      *(float4*)wv = *(const float4*)&Wt[ci][4*tc];
      *(float4*)mv = *(const float4*)&Msh[ci][4*tp];
      #pragma unroll
      for (int i = 0; i < 4; ++i)
        #pragma unroll
        for (int j = 0; j < 4; ++j)
          acc[i][j] = fmaf(wv[i], mv[j], acc[i][j]);
    }
  }
  float mean = stats_o[b*2]*(1.f/65536.f);
  float var  = stats_o[b*2+1]*(1.f/65536.f) - mean*mean;
  float rstd = rsqrtf(var + 1e-5f);
  #pragma unroll
  for (int i = 0; i < 4; ++i)
    #pragma unroll
    for (int j = 0; j < 4; ++j){
      const int co = 4*tc + i, p = p0 + 4*tp + j;
      size_t gi = ((size_t)b << 16) + ((size_t)co << 10) + p;
      size_t li = ((size_t)co << 10) + p;
      float lno = (bufo[gi] - mean)*rstd*lnog[li] + lnob[li];
      float o = sigm(osum[gi] + lno);
      out_h[gi] = o * tanh_(acc[i][j]);
    }
}

// ---------------------------------------------------------------------------
extern "C" void kernel_launch(void* const* d_in, const int* in_sizes, int n_in,
                              void* d_out, int out_size, void* d_ws, size_t ws_size,
                              hipStream_t stream)
{
  const float* x_t   = (const float*)d_in[0];
  const float* h_t   = (const float*)d_in[1];
  const float* c_t   = (const float*)d_in[2];
  const float* chist = (const float*)d_in[3];
  const float* m_t   = (const float*)d_in[4];
  const float* w_x   = (const float*)d_in[5];
  const float* lnxg  = (const float*)d_in[6];
  const float* lnxb  = (const float*)d_in[7];
  const float* w_h   = (const float*)d_in[8];
  const float* lnhg  = (const float*)d_in[9];
  const float* lnhb  = (const float*)d_in[10];
  const float* w_m   = (const float*)d_in[11];
  const float* lnmg  = (const float*)d_in[12];
  const float* lnmb  = (const float*)d_in[13];
  const float* w_o   = (const float*)d_in[14];
  const float* lnog  = (const float*)d_in[15];
  const float* lnob  = (const float*)d_in[16];
  const float* w_last= (const float*)d_in[17];
  const float* sng   = (const float*)d_in[18];
  const float* snb   = (const float*)d_in[19];
  const float* cng   = (const float*)d_in[20];
  const float* cnb   = (const float*)d_in[21];
  const float* ca_w1 = (const float*)d_in[22];
  const float* ca_b1 = (const float*)d_in[23];
  const float* calng = (const float*)d_in[24];
  const float* calnb = (const float*)d_in[25];
  const float* ca_w2 = (const float*)d_in[26];
  const float* ca_b2 = (const float*)d_in[27];
  const float* sa_w1 = (const float*)d_in[28];
  const float* salng = (const float*)d_in[29];
  const float* salnb = (const float*)d_in[30];
  const float* sa_w2 = (const float*)d_in[31];
  const float* attn_w= (const float*)d_in[32];

  float* out = (float*)d_out;
  float* ws  = (float*)d_ws;

  // workspace layout (floats). Total = 1024 + 19*N1 ~= 79.7 MB
  float* stats = ws;                        // 8 groups x 16 batches x {sum,sumsq}
  float* bufx  = ws + 1024;                 // 7*N1 raw conv_x
  float* bufh  = bufx + 7*(size_t)N1;       // 4*N1
  float* bufm  = bufh + 4*(size_t)N1;       // 3*N1
  float* ft    = bufm + 3*(size_t)N1;       // N1
  float* ig    = ft   + (size_t)N1;         // N1
  float* osum  = ig   + (size_t)N1;         // N1
  float* memo  = osum + (size_t)N1;         // 2*N1 (mem = [c_new ; m_new])
  // aliases over bufx region — only valid AFTER k_gates has consumed bufx/h/m
  float* sp    = bufx;                      // N1  c_t + spatial attn (raw)
  float* ch    = bufx + (size_t)N1;         // N1  c_t + channel attn (raw)
  float* samid = bufx + 2*(size_t)N1;       // N1  conv(sp, sa_w1) raw
  float* camid = bufx + 3*(size_t)N1;       // N1  conv(ch, ca_w1)+b raw
  float* bufo  = bufx + 4*(size_t)N1;       // N1  conv(mem, w_o) raw
  float* chl   = bufx + 5*(size_t)N1;       // 16*64*256 channel-attn logits/probs

  float* out_h = out;
  float* out_c = out + (size_t)N1;
  float* out_m = out + 2*(size_t)N1;

  k_zero<<<dim3(1), dim3(256), 0, stream>>>(stats);

  // big convs + LN stats   (stats slots: x=0, h=32, m=64)
  k_conv5<8><<<dim3(56,16), dim3(256), 0, stream>>>(x_t, 64, w_x, nullptr, bufx, 448, stats+0,
                                                    nullptr, 0.f, nullptr, nullptr);
  k_conv5<8><<<dim3(32,16), dim3(256), 0, stream>>>(h_t, 64, w_h, nullptr, bufh, 256, stats+32,
                                                    nullptr, 0.f, nullptr, nullptr);
  k_conv5<8><<<dim3(24,16), dim3(256), 0, stream>>>(m_t, 64, w_m, nullptr, bufm, 192, stats+64,
                                                    nullptr, 0.f, nullptr, nullptr);

  k_gates<<<dim3(4096), dim3(256), 0, stream>>>(bufx, bufh, bufm, lnxg, lnxb, lnhg, lnhb,
                                                lnmg, lnmb, m_t, stats,
                                                ft, ig, osum, memo, out_m);

  // attention branches  (stats: sp=96, ch=128)
  k_spat <<<dim3(16,16), dim3(256), 0, stream>>>(ft, chist, c_t, sp, stats+96);
  k_chlog<<<dim3(4,16),  dim3(256), 0, stream>>>(ft, chist, chl);
  k_chsm <<<dim3(256),   dim3(256), 0, stream>>>(chl);
  k_chout<<<dim3(16,16), dim3(256), 0, stream>>>(chl, chist, c_t, ch, stats+128);

  // 5x5 convs over LN(sp)/LN(ch)  (stats: sa=160, ca=192)
  k_conv5<4><<<dim3(16,16), dim3(256), 0, stream>>>(sp, 64, sa_w1, nullptr, samid, 64, stats+160,
                                                    stats+96, 1.f/65536.f, sng, snb);
  k_conv5<4><<<dim3(16,16), dim3(256), 0, stream>>>(ch, 64, ca_w1, ca_b1, camid, 64, stats+192,
                                                    stats+128, 1.f/65536.f, cng, cnb);

  k_attnfinal<<<dim3(16,16), dim3(256), 0, stream>>>(samid, camid, stats+160, stats+192,
                                                     salng, salnb, calng, calnb,
                                                     sa_w2, ca_w2, ca_b2, attn_w,
                                                     ig, out_c, memo);

  // conv_o over mem  (stats: o=224)
  k_conv5<4><<<dim3(16,16), dim3(256), 0, stream>>>(memo, 128, w_o, nullptr, bufo, 64, stats+224,
                                                    nullptr, 0.f, nullptr, nullptr);

  k_final<<<dim3(16,16), dim3(256), 0, stream>>>(memo, w_last, bufo, osum, stats+224,
                                                 lnog, lnob, out_h);
}

// Round 2
// 2277.048 us; speedup vs baseline: 1.2440x; 1.2440x over previous
//
#include <hip/hip_runtime.h>
#include <hip/hip_bf16.h>

#define N1 (1u << 20)   // B*NH*HW = 16*64*1024

typedef __attribute__((ext_vector_type(8))) short s8v;
typedef __attribute__((ext_vector_type(4))) float f4v;

static __device__ __forceinline__ float sigm(float x){ return 1.f/(1.f + __expf(-x)); }
static __device__ __forceinline__ float tanh_(float x){ return 1.f - 2.f/(__expf(2.f*x) + 1.f); }

static __device__ __forceinline__ ushort f2b(float f){
  union { float f; uint u; } x; x.f = f;
  uint r = x.u + 0x7FFFu + ((x.u >> 16) & 1u);
  return (ushort)(r >> 16);
}

static __device__ __forceinline__ void red_atomic2(float s, float q, float* d, int b, int t){
  #pragma unroll
  for (int m = 32; m; m >>= 1){ s += __shfl_xor(s, m); q += __shfl_xor(q, m); }
  if ((t & 63) == 0){ atomicAdd(&d[b*2], s); atomicAdd(&d[b*2+1], q); }
}

__global__ void k_zero(float* __restrict__ p){ p[threadIdx.x] = 0.f; }

// ---------------------------------------------------------------------------
// Prep: fp32 [plane][64][1024] -> bf16 transposed [plane][1024][64] (outT),
// and optional straight-cast copy [plane][64][1024] (outC).
// ---------------------------------------------------------------------------
__global__ __launch_bounds__(256) void k_prep(const float* __restrict__ src,
                                              ushort* __restrict__ outC,
                                              ushort* __restrict__ outT)
{
  const int plane = blockIdx.y;
  const int p0 = blockIdx.x << 6;
  const float* sp = src + ((size_t)plane << 16);
  __shared__ __align__(16) float T[64][68];
  const int t = threadIdx.x, c = t >> 2, g = t & 3;
  #pragma unroll
  for (int i = 0; i < 4; ++i){
    float4 f = *(const float4*)(sp + ((size_t)c << 10) + p0 + (g << 4) + (i << 2));
    *(float4*)&T[c][(g << 4) + (i << 2)] = f;
    if (outC){
      uint2 pk2;
      pk2.x = (uint)f2b(f.x) | ((uint)f2b(f.y) << 16);
      pk2.y = (uint)f2b(f.z) | ((uint)f2b(f.w) << 16);
      *(uint2*)(outC + ((((size_t)plane << 6) + c) << 10) + p0 + (g << 4) + (i << 2)) = pk2;
    }
  }
  __syncthreads();
  const int p = t >> 2, c0 = (t & 3) << 4;
  uint w4[8];
  #pragma unroll
  for (int k = 0; k < 8; ++k){
    ushort lo = f2b(T[c0 + 2*k][p]);
    ushort hi = f2b(T[c0 + 2*k + 1][p]);
    w4[k] = (uint)lo | ((uint)hi << 16);
  }
  ushort* dst = outT + ((((size_t)plane << 10) + p0 + p) << 6) + c0;
  *(uint4*)(dst)     = *(uint4*)&w4[0];
  *(uint4*)(dst + 8) = *(uint4*)&w4[4];
}

// ---------------------------------------------------------------------------
// Direct 5x5 SAME conv, NCHW, 32x32 images. COB output channels per block.
// ---------------------------------------------------------------------------
template<int COB>
__global__ __launch_bounds__(256) void k_conv5(
    const float* __restrict__ in, int Cin,
    const float* __restrict__ wgt, const float* __restrict__ bias,
    float* __restrict__ out, int Cout,
    float* __restrict__ out_stats,
    const float* __restrict__ in_stats, float in_invN,
    const float* __restrict__ in_g, const float* __restrict__ in_b)
{
  const int b   = blockIdx.y;
  const int co0 = blockIdx.x * COB;
  const int t   = threadIdx.x;
  __shared__ __align__(16) float plane[36*36];
  __shared__ __align__(16) float wsh[25][COB];
  float acc[COB][4];
  #pragma unroll
  for (int j = 0; j < COB; ++j){ acc[j][0]=0.f; acc[j][1]=0.f; acc[j][2]=0.f; acc[j][3]=0.f; }

  float mean = 0.f, rstd = 0.f;
  if (in_stats){
    float s0 = in_stats[b*2], s1 = in_stats[b*2+1];
    mean = s0 * in_invN;
    float var = s1 * in_invN - mean*mean;
    rstd = rsqrtf(var + 1e-5f);
  }
  const int px0 = t & 31, py0 = t >> 5;

  for (int ci = 0; ci < Cin; ++ci){
    __syncthreads();
    const float* ip = in + ((size_t)(b*Cin + ci) << 10);
    const float* gp = in_g ? in_g + ((size_t)ci << 10) : nullptr;
    const float* bp = in_b ? in_b + ((size_t)ci << 10) : nullptr;
    for (int i = t; i < 1296; i += 256){
      int py = i / 36, px = i - py*36;
      int y = py - 2, x = px - 2;
      float v = 0.f;
      if ((unsigned)y < 32u && (unsigned)x < 32u){
        v = ip[(y << 5) + x];
        if (gp) v = (v - mean)*rstd*gp[(y << 5) + x] + bp[(y << 5) + x];
      }
      plane[i] = v;
    }
    if (t < 25*COB){
      int j = t / 25, tap = t - j*25;
      wsh[tap][j] = wgt[((size_t)(co0 + j)*Cin + ci)*25 + tap];
    }
    __syncthreads();
    #pragma unroll
    for (int dy = 0; dy < 5; ++dy){
      #pragma unroll
      for (int dx = 0; dx < 5; ++dx){
        const int tap = dy*5 + dx;
        float pv[4];
        #pragma unroll
        for (int pi = 0; pi < 4; ++pi) pv[pi] = plane[(py0 + 8*pi + dy)*36 + px0 + dx];
        float wreg[COB];
        *(float4*)&wreg[0] = *(const float4*)&wsh[tap][0];
        if constexpr (COB == 8) *(float4*)&wreg[4] = *(const float4*)&wsh[tap][4];
        #pragma unroll
        for (int j = 0; j < COB; ++j){
          #pragma unroll
          for (int pi = 0; pi < 4; ++pi) acc[j][pi] = fmaf(wreg[j], pv[pi], acc[j][pi]);
        }
      }
    }
  }
  float lsum = 0.f, lsq = 0.f;
  #pragma unroll
  for (int j = 0; j < COB; ++j){
    float bb = bias ? bias[co0 + j] : 0.f;
    float* op = out + ((size_t)(b*Cout + co0 + j) << 10) + t;
    #pragma unroll
    for (int pi = 0; pi < 4; ++pi){
      float v = acc[j][pi] + bb;
      op[pi << 8] = v;
      lsum += v; lsq += v*v;
    }
  }
  if (out_stats) red_atomic2(lsum, lsq, out_stats, b, t);
}

// ---------------------------------------------------------------------------
// Gates
// ---------------------------------------------------------------------------
__global__ __launch_bounds__(256) void k_gates(
    const float* __restrict__ bufx, const float* __restrict__ bufh, const float* __restrict__ bufm,
    const float* __restrict__ lnxg, const float* __restrict__ lnxb,
    const float* __restrict__ lnhg, const float* __restrict__ lnhb,
    const float* __restrict__ lnmg, const float* __restrict__ lnmb,
    const float* __restrict__ m_t, const float* __restrict__ stats,
    float* __restrict__ ft, float* __restrict__ ig, float* __restrict__ osum,
    float* __restrict__ memo, float* __restrict__ out_m)
{
  const int idx = blockIdx.x*256 + threadIdx.x;
  const int b = idx >> 16, rem = idx & 65535;
  const int c = rem >> 10, p = rem & 1023;

  float mx = stats[b*2]      * (1.f/458752.f);
  float vx = stats[b*2+1]    * (1.f/458752.f) - mx*mx;  float rx = rsqrtf(vx + 1e-5f);
  float mh = stats[32+b*2]   * (1.f/262144.f);
  float vh = stats[32+b*2+1] * (1.f/262144.f) - mh*mh;  float rh = rsqrtf(vh + 1e-5f);
  float mm = stats[64+b*2]   * (1.f/196608.f);
  float vm = stats[64+b*2+1] * (1.f/196608.f) - mm*mm;  float rm = rsqrtf(vm + 1e-5f);

  auto LX = [&](int k){
    size_t ch = (size_t)k*64 + c; size_t gi = ((size_t)b*448 + ch)*1024 + p; size_t li = ch*1024 + p;
    return (bufx[gi] - mx)*rx*lnxg[li] + lnxb[li]; };
  auto LH = [&](int k){
    size_t ch = (size_t)k*64 + c; size_t gi = ((size_t)b*256 + ch)*1024 + p; size_t li = ch*1024 + p;
    return (bufh[gi] - mh)*rh*lnhg[li] + lnhb[li]; };
  auto LM = [&](int k){
    size_t ch = (size_t)k*64 + c; size_t gi = ((size_t)b*192 + ch)*1024 + p; size_t li = ch*1024 + p;
    return (bufm[gi] - mm)*rm*lnmg[li] + lnmb[li]; };

  float i_t = sigm(LX(0) + LH(0));
  float f_t = sigm(LX(1) + LH(1) + 1.f);
  float g_t = tanh_(LX(2) + LH(2));
  float i_p = sigm(LX(3) + LM(0));
  float f_p = sigm(LX(4) + LM(1) + 1.f);
  float g_p = tanh_(LX(5) + LM(2));
  float ox = LX(6), oh = LH(3);

  ft[idx]   = f_t;
  ig[idx]   = i_t * g_t;
  osum[idx] = ox + oh;
  float mn = f_p * m_t[idx] + i_p * g_p;
  out_m[idx] = mn;
  memo[((size_t)(b*128 + 64 + c) << 10) + p] = mn;
}

// ---------------------------------------------------------------------------
// Spatial attention via bf16 MFMA (fixed-shift softmax, additive num/den).
// Block: 64 px (4 waves x 16 px), streams all 4096 kv in 64-kv chunks.
// qT  : bf16 [b][1024 px][64 ch]   (A operand, QK)
// kvT : bf16 [b*4][1024 kv][64 ch] (B^T operand, QK: [n=kv][k=ch])
// kvC : bf16 [b*4][64 ch][1024 kv] (B^T operand, PV: [n=ch][k=kv])
// ---------------------------------------------------------------------------
__global__ __launch_bounds__(256) void k_spat_mfma(
    const ushort* __restrict__ qT, const ushort* __restrict__ kvC, const ushort* __restrict__ kvT,
    const float* __restrict__ c_t, float* __restrict__ sp_raw, float* __restrict__ stats)
{
  const int p0 = blockIdx.x << 6, b = blockIdx.y;
  const int t = threadIdx.x, w = t >> 6, l = t & 63;
  const int lane16 = l & 15, quad = l >> 4;
  __shared__ __align__(16) ushort Kt[64][72];   // [kv][ch] padded
  __shared__ __align__(16) ushort Kc[64][72];   // [ch][kv] padded
  __shared__ __align__(16) ushort Eb[64][72];   // [px(4 waves x16)][kv] padded
  __shared__ __align__(16) float  XO[64][65];   // [ch][px] fp32 out transpose

  s8v qa0, qa1;
  {
    const ushort* qr = qT + ((((size_t)b << 10) + p0 + (w << 4) + lane16) << 6) + (quad << 3);
    qa0 = *(const s8v*)(qr);
    qa1 = *(const s8v*)(qr + 32);
  }
  f4v o0 = {0.f,0.f,0.f,0.f}, o1 = o0, o2 = o0, o3 = o0, dacc = o0;
  const short oneb = (short)0x3F80;
  const s8v ones = { oneb, oneb, oneb, oneb, oneb, oneb, oneb, oneb };

  const int r = t >> 2, g4 = (t & 3) << 4;
  for (int chunk = 0; chunk < 64; ++chunk){
    const int lidx = chunk >> 4, pk = (chunk & 15) << 6;
    __syncthreads();
    {
      const ushort* sc = kvC + ((((size_t)(b*4 + lidx) << 6) + r) << 10) + pk + g4;
      *(uint4*)&Kc[r][g4]     = *(const uint4*)(sc);
      *(uint4*)&Kc[r][g4 + 8] = *(const uint4*)(sc + 8);
      const ushort* st = kvT + ((((size_t)(b*4 + lidx) << 10) + pk + r) << 6) + g4;
      *(uint4*)&Kt[r][g4]     = *(const uint4*)(st);
      *(uint4*)&Kt[r][g4 + 8] = *(const uint4*)(st + 8);
    }
    __syncthreads();
    // QK^T -> E (bf16) into Eb rows of this wave
    #pragma unroll
    for (int nt = 0; nt < 4; ++nt){
      const ushort* bt = &Kt[(nt << 4) + lane16][quad << 3];
      s8v b0 = *(const s8v*)(bt);
      s8v b1 = *(const s8v*)(bt + 32);
      f4v s = {0.f,0.f,0.f,0.f};
      s = __builtin_amdgcn_mfma_f32_16x16x32_bf16(qa0, b0, s, 0, 0, 0);
      s = __builtin_amdgcn_mfma_f32_16x16x32_bf16(qa1, b1, s, 0, 0, 0);
      #pragma unroll
      for (int i = 0; i < 4; ++i){
        float e = __expf(s[i] - 12.f);
        Eb[(w << 4) + (quad << 2) + i][(nt << 4) + lane16] = f2b(e);
      }
    }
    // PV + denominator (ones-B MFMA)
    #pragma unroll
    for (int ks = 0; ks < 2; ++ks){
      s8v ea = *(const s8v*)&Eb[(w << 4) + lane16][(ks << 5) + (quad << 3)];
      dacc = __builtin_amdgcn_mfma_f32_16x16x32_bf16(ea, ones, dacc, 0, 0, 0);
      s8v bc0 = *(const s8v*)&Kc[ 0 + lane16][(ks << 5) + (quad << 3)];
      s8v bc1 = *(const s8v*)&Kc[16 + lane16][(ks << 5) + (quad << 3)];
      s8v bc2 = *(const s8v*)&Kc[32 + lane16][(ks << 5) + (quad << 3)];
      s8v bc3 = *(const s8v*)&Kc[48 + lane16][(ks << 5) + (quad << 3)];
      o0 = __builtin_amdgcn_mfma_f32_16x16x32_bf16(ea, bc0, o0, 0, 0, 0);
      o1 = __builtin_amdgcn_mfma_f32_16x16x32_bf16(ea, bc1, o1, 0, 0, 0);
      o2 = __builtin_amdgcn_mfma_f32_16x16x32_bf16(ea, bc2, o2, 0, 0, 0);
      o3 = __builtin_amdgcn_mfma_f32_16x16x32_bf16(ea, bc3, o3, 0, 0, 0);
    }
  }
  // normalize into XO[ch][px]
  {
    float inv0 = 1.f/dacc[0], inv1 = 1.f/dacc[1], inv2 = 1.f/dacc[2], inv3 = 1.f/dacc[3];
    const int pxl = (w << 4) + (quad << 2);
    XO[ 0 + lane16][pxl+0] = o0[0]*inv0; XO[ 0 + lane16][pxl+1] = o0[1]*inv1;
    XO[ 0 + lane16][pxl+2] = o0[2]*inv2; XO[ 0 + lane16][pxl+3] = o0[3]*inv3;
    XO[16 + lane16][pxl+0] = o1[0]*inv0; XO[16 + lane16][pxl+1] = o1[1]*inv1;
    XO[16 + lane16][pxl+2] = o1[2]*inv2; XO[16 + lane16][pxl+3] = o1[3]*inv3;
    XO[32 + lane16][pxl+0] = o2[0]*inv0; XO[32 + lane16][pxl+1] = o2[1]*inv1;
    XO[32 + lane16][pxl+2] = o2[2]*inv2; XO[32 + lane16][pxl+3] = o2[3]*inv3;
    XO[48 + lane16][pxl+0] = o3[0]*inv0; XO[48 + lane16][pxl+1] = o3[1]*inv1;
    XO[48 + lane16][pxl+2] = o3[2]*inv2; XO[48 + lane16][pxl+3] = o3[3]*inv3;
  }
  __syncthreads();
  // coalesced output pass: ch = t>>2, 16 px
  {
    const int ch = t >> 2;
    float lsum = 0.f, lsq = 0.f;
    #pragma unroll
    for (int i = 0; i < 4; ++i){
      size_t gi = ((size_t)b << 16) + ((size_t)ch << 10) + p0 + g4 + (i << 2);
      float4 cv = *(const float4*)(c_t + gi);
      float4 ov;
      ov.x = cv.x + XO[ch][g4 + (i << 2) + 0];
      ov.y = cv.y + XO[ch][g4 + (i << 2) + 1];
      ov.z = cv.z + XO[ch][g4 + (i << 2) + 2];
      ov.w = cv.w + XO[ch][g4 + (i << 2) + 3];
      *(float4*)(sp_raw + gi) = ov;
      lsum += ov.x + ov.y + ov.z + ov.w;
      lsq  += ov.x*ov.x + ov.y*ov.y + ov.z*ov.z + ov.w*ov.w;
    }
    red_atomic2(lsum, lsq, stats, b, t);
  }
}

// ---------------------------------------------------------------------------
// Channel attention: logits GEMM, wave softmax, AV GEMM
// ---------------------------------------------------------------------------
__global__ __launch_bounds__(256) void k_chlog(
    const float* __restrict__ ft, const float* __restrict__ chist, float* __restrict__ lg)
{
  const int l = blockIdx.x, b = blockIdx.y, t = threadIdx.x;
  const int tc = t & 15, tk = t >> 4;
  __shared__ __align__(16) float Fs[64][68];
  __shared__ __align__(16) float Ks[64][68];
  float acc[4][4] = {};
  for (int pc = 0; pc < 16; ++pc){
    __syncthreads();
    {
      const int j = t & 63, c0 = t >> 6;
      const float* fp = ft + ((size_t)b << 16) + (pc << 6) + j;
      const float* kp = chist + (((size_t)(b*4 + l)) << 16) + (pc << 6) + j;
      #pragma unroll
      for (int c = c0; c < 64; c += 4){ Fs[c][j] = fp[(size_t)c << 10]; Ks[c][j] = kp[(size_t)c << 10]; }
    }
    __syncthreads();
    #pragma unroll 4
    for (int p = 0; p < 64; p += 4){
      float fv[4][4], kv[4][4];
      #pragma unroll
      for (int i = 0; i < 4; ++i) *(float4*)fv[i] = *(const float4*)&Fs[4*tc+i][p];
      #pragma unroll
      for (int j = 0; j < 4; ++j) *(float4*)kv[j] = *(const float4*)&Ks[4*tk+j][p];
      #pragma unroll
      for (int i = 0; i < 4; ++i)
        #pragma unroll
        for (int j = 0; j < 4; ++j)
          #pragma unroll
          for (int k = 0; k < 4; ++k)
            acc[i][j] = fmaf(fv[i][k], kv[j][k], acc[i][j]);
    }
  }
  #pragma unroll
  for (int i = 0; i < 4; ++i)
    #pragma unroll
    for (int j = 0; j < 4; ++j)
      lg[((size_t)(b*64 + 4*tc + i) << 8) + (l << 6) + 4*tk + j] = acc[i][j];
}

__global__ __launch_bounds__(256) void k_chsm(float* __restrict__ a)
{
  const int row  = blockIdx.x*4 + (threadIdx.x >> 6);
  const int lane = threadIdx.x & 63;
  float* rp = a + ((size_t)row << 8);
  float v0 = rp[lane], v1 = rp[lane+64], v2 = rp[lane+128], v3 = rp[lane+192];
  float mx = fmaxf(fmaxf(v0, v1), fmaxf(v2, v3));
  #pragma unroll
  for (int m = 32; m; m >>= 1) mx = fmaxf(mx, __shfl_xor(mx, m));
  v0 = __expf(v0 - mx); v1 = __expf(v1 - mx); v2 = __expf(v2 - mx); v3 = __expf(v3 - mx);
  float s = v0 + v1 + v2 + v3;
  #pragma unroll
  for (int m = 32; m; m >>= 1) s += __shfl_xor(s, m);
  float inv = 1.f / s;
  rp[lane] = v0*inv; rp[lane+64] = v1*inv; rp[lane+128] = v2*inv; rp[lane+192] = v3*inv;
}

__global__ __launch_bounds__(256) void k_chout(
    const float* __restrict__ a, const float* __restrict__ chist,
    const float* __restrict__ c_t, float* __restrict__ ch_raw, float* __restrict__ stats)
{
  const int p0 = blockIdx.x << 6, b = blockIdx.y, t = threadIdx.x;
  const int tc = t & 15, tp = t >> 4;
  __shared__ __align__(16) float As[64][68];
  __shared__ __align__(16) float Ks[64][68];
  float acc[4][4] = {};
  for (int h = 0; h < 4; ++h){
    __syncthreads();
    {
      const int j = t & 63, c0 = t >> 6;
      const float* ap = a + ((size_t)b << 14) + (h << 6) + j;
      #pragma unroll
      for (int c = c0; c < 64; c += 4) As[j][c] = ap[(size_t)c << 8];
      const int p = t & 63, j0 = t >> 6;
      const float* kp = chist + (((size_t)(b*4 + h)) << 16) + p0 + p;
      #pragma unroll
      for (int jj = j0; jj < 64; jj += 4) Ks[jj][p] = kp[(size_t)jj << 10];
    }
    __syncthreads();
    #pragma unroll 4
    for (int k = 0; k < 64; k += 4){
      float av[4][4], kv[4][4];
      #pragma unroll
      for (int j = 0; j < 4; ++j){ *(float4*)av[j] = *(const float4*)&As[k+j][4*tc];
                                   *(float4*)kv[j] = *(const float4*)&Ks[k+j][4*tp]; }
      #pragma unroll
      for (int ci = 0; ci < 4; ++ci)
        #pragma unroll
        for (int pi = 0; pi < 4; ++pi)
          #pragma unroll
          for (int j = 0; j < 4; ++j)
            acc[ci][pi] = fmaf(av[j][ci], kv[j][pi], acc[ci][pi]);
    }
  }
  float lsum = 0.f, lsq = 0.f;
  #pragma unroll
  for (int ci = 0; ci < 4; ++ci)
    #pragma unroll
    for (int pi = 0; pi < 4; ++pi){
      size_t gi = ((size_t)b << 16) + ((size_t)(4*tc + ci) << 10) + p0 + 4*tp + pi;
      float v = c_t[gi] + acc[ci][pi];
      ch_raw[gi] = v;
      lsum += v; lsq += v*v;
    }
  red_atomic2(lsum, lsq, stats, b, t);
}

// ---------------------------------------------------------------------------
// LN+relu both attention branches, 1x1 convs, sum, 1x1 attn_w, c_new
// ---------------------------------------------------------------------------
__global__ __launch_bounds__(256) void k_attnfinal(
    const float* __restrict__ samid, const float* __restrict__ camid,
    const float* __restrict__ stats_sa, const float* __restrict__ stats_ca,
    const float* __restrict__ salng, const float* __restrict__ salnb,
    const float* __restrict__ calng, const float* __restrict__ calnb,
    const float* __restrict__ wsa2, const float* __restrict__ wca2,
    const float* __restrict__ cab2, const float* __restrict__ wat,
    const float* __restrict__ ig, float* __restrict__ out_c, float* __restrict__ memo)
{
  const int p0 = blockIdx.x << 6, b = blockIdx.y, t = threadIdx.x;
  const int tc = t & 15, tp = t >> 4;
  __shared__ __align__(16) float R[64][68];
  __shared__ __align__(16) float Wl[64][68];
  __shared__ __align__(16) float Ms[64][68];
  const float invN = 1.f/65536.f;
  float acc[4][4] = {};
  #pragma unroll
  for (int pass = 0; pass < 2; ++pass){
    const float* mid = pass ? camid : samid;
    const float* st  = pass ? stats_ca : stats_sa;
    const float* g   = pass ? calng : salng;
    const float* bb  = pass ? calnb : salnb;
    const float* w   = pass ? wca2  : wsa2;
    float mean = st[b*2]*invN;
    float var  = st[b*2+1]*invN - mean*mean;
    float rstd = rsqrtf(var + 1e-5f);
    __syncthreads();
    {
      const int j = t & 63, c0 = t >> 6;
      for (int ci = c0; ci < 64; ci += 4){
        size_t gi = ((size_t)b << 16) + ((size_t)ci << 10) + p0 + j;
        size_t li = ((size_t)ci << 10) + p0 + j;
        float v = (mid[gi] - mean)*rstd*g[li] + bb[li];
        R[ci][j] = fmaxf(v, 0.f);
      }
      const int ci2 = t & 63, c20 = t >> 6;
      for (int c2 = c20; c2 < 64; c2 += 4) Wl[ci2][c2] = w[((size_t)c2 << 6) + ci2];
    }
    __syncthreads();
    for (int ci = 0; ci < 64; ++ci){
      float wv[4], rv[4];
      *(float4*)wv = *(const float4*)&Wl[ci][4*tc];
      *(float4*)rv = *(const float4*)&R[ci][4*tp];
      #pragma unroll
      for (int i = 0; i < 4; ++i)
        #pragma unroll
        for (int j = 0; j < 4; ++j)
          acc[i][j] = fmaf(wv[i], rv[j], acc[i][j]);
    }
  }
  {
    float b2[4];
    #pragma unroll
    for (int i = 0; i < 4; ++i) b2[i] = cab2[4*tc + i];
    #pragma unroll
    for (int i = 0; i < 4; ++i)
      #pragma unroll
      for (int j = 0; j < 4; ++j)
        Ms[4*tc+i][4*tp+j] = acc[i][j] + b2[i];
  }
  __syncthreads();
  {
    const int ci2 = t & 63, c20 = t >> 6;
    for (int c2 = c20; c2 < 64; c2 += 4) Wl[ci2][c2] = wat[((size_t)c2 << 6) + ci2];
  }
  __syncthreads();
  float acc2[4][4] = {};
  for (int c2 = 0; c2 < 64; ++c2){
    float wv[4], mv[4];
    *(float4*)wv = *(const float4*)&Wl[c2][4*tc];
    *(float4*)mv = *(const float4*)&Ms[c2][4*tp];
    #pragma unroll
    for (int i = 0; i < 4; ++i)
      #pragma unroll
      for (int j = 0; j < 4; ++j)
        acc2[i][j] = fmaf(wv[i], mv[j], acc2[i][j]);
  }
  #pragma unroll
  for (int i = 0; i < 4; ++i)
    #pragma unroll
    for (int j = 0; j < 4; ++j){
      size_t gi = ((size_t)b << 16) + ((size_t)(4*tc + i) << 10) + p0 + 4*tp + j;
      float v = acc2[i][j] + ig[gi];
      out_c[gi] = v;
      memo[((size_t)(b*128 + 4*tc + i) << 10) + p0 + 4*tp + j] = v;
    }
}

// ---------------------------------------------------------------------------
__global__ __launch_bounds__(256) void k_final(
    const float* __restrict__ memo, const float* __restrict__ wlast,
    const float* __restrict__ bufo, const float* __restrict__ osum,
    const float* __restrict__ stats_o, const float* __restrict__ lnog, const float* __restrict__ lnob,
    float* __restrict__ out_h)
{
  const int p0 = blockIdx.x << 6, b = blockIdx.y, t = threadIdx.x;
  const int tc = t & 15, tp = t >> 4;
  __shared__ __align__(16) float Msh[64][68];
  __shared__ __align__(16) float Wt[64][68];
  float acc[4][4] = {};
  #pragma unroll
  for (int half = 0; half < 2; ++half){
    __syncthreads();
    {
      const int j = t & 63, c0 = t >> 6;
      for (int ci = c0; ci < 64; ci += 4)
        Msh[ci][j] = memo[((size_t)(b*128 + half*64 + ci) << 10) + p0 + j];
      const int ci2 = t & 63, co0 = t >> 6;
      for (int co = co0; co < 64; co += 4) Wt[ci2][co] = wlast[((size_t)co << 7) + half*64 + ci2];
    }
    __syncthreads();
    for (int ci = 0; ci < 64; ++ci){
      float wv[4], mv[4];
      *(float4*)wv = *(const float4*)&Wt[ci][4*tc];
      *(float4*)mv = *(const float4*)&Msh[ci][4*tp];
      #pragma unroll
      for (int i = 0; i < 4; ++i)
        #pragma unroll
        for (int j = 0; j < 4; ++j)
          acc[i][j] = fmaf(wv[i], mv[j], acc[i][j]);
    }
  }
  float mean = stats_o[b*2]*(1.f/65536.f);
  float var  = stats_o[b*2+1]*(1.f/65536.f) - mean*mean;
  float rstd = rsqrtf(var + 1e-5f);
  #pragma unroll
  for (int i = 0; i < 4; ++i)
    #pragma unroll
    for (int j = 0; j < 4; ++j){
      const int co = 4*tc + i, p = p0 + 4*tp + j;
      size_t gi = ((size_t)b << 16) + ((size_t)co << 10) + p;
      size_t li = ((size_t)co << 10) + p;
      float lno = (bufo[gi] - mean)*rstd*lnog[li] + lnob[li];
      float o = sigm(osum[gi] + lno);
      out_h[gi] = o * tanh_(acc[i][j]);
    }
}

// ---------------------------------------------------------------------------
extern "C" void kernel_launch(void* const* d_in, const int* in_sizes, int n_in,
                              void* d_out, int out_size, void* d_ws, size_t ws_size,
                              hipStream_t stream)
{
  const float* x_t   = (const float*)d_in[0];
  const float* h_t   = (const float*)d_in[1];
  const float* c_t   = (const float*)d_in[2];
  const float* chist = (const float*)d_in[3];
  const float* m_t   = (const float*)d_in[4];
  const float* w_x   = (const float*)d_in[5];
  const float* lnxg  = (const float*)d_in[6];
  const float* lnxb  = (const float*)d_in[7];
  const float* w_h   = (const float*)d_in[8];
  const float* lnhg  = (const float*)d_in[9];
  const float* lnhb  = (const float*)d_in[10];
  const float* w_m   = (const float*)d_in[11];
  const float* lnmg  = (const float*)d_in[12];
  const float* lnmb  = (const float*)d_in[13];
  const float* w_o   = (const float*)d_in[14];
  const float* lnog  = (const float*)d_in[15];
  const float* lnob  = (const float*)d_in[16];
  const float* w_last= (const float*)d_in[17];
  const float* sng   = (const float*)d_in[18];
  const float* snb   = (const float*)d_in[19];
  const float* cng   = (const float*)d_in[20];
  const float* cnb   = (const float*)d_in[21];
  const float* ca_w1 = (const float*)d_in[22];
  const float* ca_b1 = (const float*)d_in[23];
  const float* calng = (const float*)d_in[24];
  const float* calnb = (const float*)d_in[25];
  const float* ca_w2 = (const float*)d_in[26];
  const float* ca_b2 = (const float*)d_in[27];
  const float* sa_w1 = (const float*)d_in[28];
  const float* salng = (const float*)d_in[29];
  const float* salnb = (const float*)d_in[30];
  const float* sa_w2 = (const float*)d_in[31];
  const float* attn_w= (const float*)d_in[32];

  float* out = (float*)d_out;
  float* ws  = (float*)d_ws;

  // workspace layout (floats). Total = 1024 + 19*N1 ~= 79.7 MB
  float* stats = ws;                        // 8 groups x 16 batches x {sum,sumsq}
  float* bufx  = ws + 1024;                 // 7*N1 raw conv_x
  float* bufh  = bufx + 7*(size_t)N1;       // 4*N1
  float* bufm  = bufh + 4*(size_t)N1;       // 3*N1
  float* ft    = bufm + 3*(size_t)N1;       // N1
  float* ig    = ft   + (size_t)N1;         // N1
  float* osum  = ig   + (size_t)N1;         // N1
  float* memo  = osum + (size_t)N1;         // 2*N1
  // aliases valid AFTER k_gates consumed bufx/h/m:
  float* sp    = bufx;                      // N1
  float* ch    = bufx + (size_t)N1;         // N1
  float* samid = bufx + 2*(size_t)N1;       // N1
  float* camid = bufx + 3*(size_t)N1;       // N1
  float* bufo  = bufx + 4*(size_t)N1;       // N1
  float* chl   = bufx + 5*(size_t)N1;       // channel-attn logits/probs
  ushort* kvC  = (ushort*)bufh;             // 4M bf16 (8 MB)  in bufh region (16 MB)
  ushort* kvT  = kvC + 4*(size_t)N1;        // 4M bf16 (8 MB)
  ushort* qT   = (ushort*)bufm;             // 1M bf16 (2 MB)  in bufm region

  float* out_h = out;
  float* out_c = out + (size_t)N1;
  float* out_m = out + 2*(size_t)N1;

  k_zero<<<dim3(1), dim3(256), 0, stream>>>(stats);

  // big convs + LN stats   (stats slots: x=0, h=32, m=64)
  k_conv5<8><<<dim3(56,16), dim3(256), 0, stream>>>(x_t, 64, w_x, nullptr, bufx, 448, stats+0,
                                                    nullptr, 0.f, nullptr, nullptr);
  k_conv5<8><<<dim3(32,16), dim3(256), 0, stream>>>(h_t, 64, w_h, nullptr, bufh, 256, stats+32,
                                                    nullptr, 0.f, nullptr, nullptr);
  k_conv5<8><<<dim3(24,16), dim3(256), 0, stream>>>(m_t, 64, w_m, nullptr, bufm, 192, stats+64,
                                                    nullptr, 0.f, nullptr, nullptr);

  k_gates<<<dim3(4096), dim3(256), 0, stream>>>(bufx, bufh, bufm, lnxg, lnxb, lnhg, lnhb,
                                                lnmg, lnmb, m_t, stats,
                                                ft, ig, osum, memo, out_m);

  // bf16 prep (after gates: bufh/bufm are free, ft exists)
  k_prep<<<dim3(16,64), dim3(256), 0, stream>>>(chist, kvC, kvT);
  k_prep<<<dim3(16,16), dim3(256), 0, stream>>>(ft, nullptr, qT);

  // attention branches  (stats: sp=96, ch=128)
  k_spat_mfma<<<dim3(16,16), dim3(256), 0, stream>>>(qT, kvC, kvT, c_t, sp, stats+96);
  k_chlog<<<dim3(4,16),  dim3(256), 0, stream>>>(ft, chist, chl);
  k_chsm <<<dim3(256),   dim3(256), 0, stream>>>(chl);
  k_chout<<<dim3(16,16), dim3(256), 0, stream>>>(chl, chist, c_t, ch, stats+128);

  // 5x5 convs over LN(sp)/LN(ch)  (stats: sa=160, ca=192)
  k_conv5<4><<<dim3(16,16), dim3(256), 0, stream>>>(sp, 64, sa_w1, nullptr, samid, 64, stats+160,
                                                    stats+96, 1.f/65536.f, sng, snb);
  k_conv5<4><<<dim3(16,16), dim3(256), 0, stream>>>(ch, 64, ca_w1, ca_b1, camid, 64, stats+192,
                                                    stats+128, 1.f/65536.f, cng, cnb);

  k_attnfinal<<<dim3(16,16), dim3(256), 0, stream>>>(samid, camid, stats+160, stats+192,
                                                     salng, salnb, calng, calnb,
                                                     sa_w2, ca_w2, ca_b2, attn_w,
                                                     ig, out_c, memo);

  // conv_o over mem  (stats: o=224)
  k_conv5<4><<<dim3(16,16), dim3(256), 0, stream>>>(memo, 128, w_o, nullptr, bufo, 64, stats+224,
                                                    nullptr, 0.f, nullptr, nullptr);

  k_final<<<dim3(16,16), dim3(256), 0, stream>>>(memo, w_last, bufo, osum, stats+224,
                                                 lnog, lnob, out_h);
}

// Round 3
// 1042.193 us; speedup vs baseline: 2.7180x; 2.1849x over previous
//
#include <hip/hip_runtime.h>
#include <hip/hip_bf16.h>

#define N1 (1u << 20)   // B*NH*HW = 16*64*1024

typedef __attribute__((ext_vector_type(8))) short s8v;
typedef __attribute__((ext_vector_type(4))) float f4v;

static __device__ __forceinline__ float sigm(float x){ return 1.f/(1.f + __expf(-x)); }
static __device__ __forceinline__ float tanh_(float x){ return 1.f - 2.f/(__expf(2.f*x) + 1.f); }

static __device__ __forceinline__ ushort f2b(float f){
  union { float f; uint u; } x; x.f = f;
  uint r = x.u + 0x7FFFu + ((x.u >> 16) & 1u);
  return (ushort)(r >> 16);
}

static __device__ __forceinline__ void red_atomic2(float s, float q, float* d, int b, int t){
  #pragma unroll
  for (int m = 32; m; m >>= 1){ s += __shfl_xor(s, m); q += __shfl_xor(q, m); }
  if ((t & 63) == 0){ atomicAdd(&d[b*2], s); atomicAdd(&d[b*2+1], q); }
}

__global__ void k_zero(float* __restrict__ p){ p[threadIdx.x] = 0.f; }

// ---------------------------------------------------------------------------
// Weight prep: fp32 [Co][Ci][5][5] -> bf16 [tap][Co][Ci], three convs fused.
// ---------------------------------------------------------------------------
__global__ __launch_bounds__(256) void k_wprep3(
    const float* __restrict__ sA, ushort* __restrict__ dA, int CoA, int CiA, int nA,
    const float* __restrict__ sB, ushort* __restrict__ dB, int CoB, int CiB, int nB,
    const float* __restrict__ sC, ushort* __restrict__ dC, int CoC, int CiC, int nC)
{
  int idx = blockIdx.x*256 + threadIdx.x;
  const float* s; ushort* d; int Co, Ci;
  if (idx < nA){ s=sA; d=dA; Co=CoA; Ci=CiA; }
  else if ((idx -= nA) < nB){ s=sB; d=dB; Co=CoB; Ci=CiB; }
  else if ((idx -= nB) < nC){ s=sC; d=dC; Co=CoC; Ci=CiC; }
  else return;
  int ci = idx % Ci; int r = idx / Ci; int co = r % Co; int tap = r / Co;
  d[idx] = f2b(s[((size_t)(co*Ci + ci))*25 + tap]);
}

// ---------------------------------------------------------------------------
// MFMA 5x5 SAME conv, NCHW, 32x32 imgs. Block: MT*16 co x 8 rows (256 px).
// Wave w: rows {2w, 2w+1}, all 32 cols -> 4 n-tiles of 16 px. MT m-tiles.
// Per tap: A = W_tap[co][ci32], B = in[ci32][px shifted]. K=32 per MFMA.
// Optional LN-on-load of input (stats+g+b), bias, output stats.
// ---------------------------------------------------------------------------
template<int MT>
__global__ __launch_bounds__(256, 2) void k_conv5m(
    const float* __restrict__ in, int Cin,
    const ushort* __restrict__ wB, const float* __restrict__ bias,
    float* __restrict__ out, int Cout,
    float* __restrict__ out_stats,
    const float* __restrict__ in_stats, float in_invN,
    const float* __restrict__ in_g, const float* __restrict__ in_b)
{
  const int b = blockIdx.y;
  const int cog = blockIdx.x >> 2, pxblk = blockIdx.x & 3;
  const int co0 = cog * (MT*16);
  const int r0 = pxblk << 3;
  const int t = threadIdx.x, w = t >> 6, l = t & 63;
  const int lane16 = l & 15, quad = l >> 4;

  __shared__ __align__(16) ushort S[12*36*40];        // [row][col][ci+pad]
  __shared__ __align__(16) ushort Wsh[2][MT*16*40];   // dbuf [co][ci+pad]

  f4v acc[MT][4];
  #pragma unroll
  for (int mi = 0; mi < MT; ++mi)
    #pragma unroll
    for (int n = 0; n < 4; ++n) acc[mi][n] = (f4v){0.f,0.f,0.f,0.f};

  float mean = 0.f, rstd = 0.f;
  if (in_stats){
    float s0 = in_stats[b*2], s1 = in_stats[b*2+1];
    mean = s0 * in_invN;
    rstd = rsqrtf(s1 * in_invN - mean*mean + 1e-5f);
  }

  const int tl = t & 31, th = t >> 5;
  const int tw = t & 3, rj0 = t >> 2;

  const int ncc = Cin >> 5;
  for (int cc = 0; cc < ncc; ++cc){
    __syncthreads();   // previous compute done reading S/Wsh
    // ---- stage input stripe (rows r0-2..r0+9, cols -2..33, 32 ci) ----
    #pragma unroll 4
    for (int j = th; j < 384; j += 8){
      const int ci = j & 31, row = j >> 5;
      const int imgrow = r0 - 2 + row;
      float v = 0.f;
      if ((unsigned)imgrow < 32u){
        const size_t pidx = ((size_t)imgrow << 5) + tl;
        v = in[(((size_t)(b*Cin + (cc<<5) + ci)) << 10) + pidx];
        if (in_g){
          const size_t li = (((size_t)((cc<<5) + ci)) << 10) + pidx;
          v = (v - mean)*rstd*in_g[li] + in_b[li];
        }
      }
      S[(row*36 + tl + 2)*40 + ci] = f2b(v);
      if (tl < 4) S[(row*36 + ((tl < 2) ? tl : (tl + 32)))*40 + ci] = 0;
    }
    // ---- stage tap 0 weights ----
    #pragma unroll
    for (int rj = 0; rj < MT*16; rj += 64){
      const int co = rj + rj0;
      uint4 wv = make_uint4(0,0,0,0);
      if (co0 + co < Cout)
        wv = *(const uint4*)(wB + ((size_t)(co0 + co))*Cin + (cc<<5) + (tw<<3));
      *(uint4*)&Wsh[0][co*40 + (tw<<3)] = wv;
    }
    __syncthreads();
    // ---- tap loop, double-buffered weights ----
    for (int tap = 0; tap < 25; ++tap){
      const int dy = tap/5, dx = tap - dy*5;
      s8v a[MT];
      #pragma unroll
      for (int mi = 0; mi < MT; ++mi)
        a[mi] = *(const s8v*)&Wsh[tap & 1][(mi*16 + lane16)*40 + (quad<<3)];
      #pragma unroll
      for (int n = 0; n < 4; ++n){
        const int row = (w<<1) + (n>>1) + dy;
        const int col = ((n&1)<<4) + lane16 + dx;
        s8v bb = *(const s8v*)&S[(row*36 + col)*40 + (quad<<3)];
        #pragma unroll
        for (int mi = 0; mi < MT; ++mi)
          acc[mi][n] = __builtin_amdgcn_mfma_f32_16x16x32_bf16(a[mi], bb, acc[mi][n], 0, 0, 0);
      }
      if (tap < 24){
        #pragma unroll
        for (int rj = 0; rj < MT*16; rj += 64){
          const int co = rj + rj0;
          uint4 wv = make_uint4(0,0,0,0);
          if (co0 + co < Cout)
            wv = *(const uint4*)(wB + ((size_t)((tap+1)*Cout + co0 + co))*Cin + (cc<<5) + (tw<<3));
          *(uint4*)&Wsh[(tap+1) & 1][co*40 + (tw<<3)] = wv;
        }
      }
      __syncthreads();
    }
  }
  // ---- epilogue: store + stats ----
  float lsum = 0.f, lsq = 0.f;
  #pragma unroll
  for (int mi = 0; mi < MT; ++mi){
    const int co = co0 + mi*16 + (quad<<2);
    #pragma unroll
    for (int n = 0; n < 4; ++n){
      const int row = r0 + (w<<1) + (n>>1);
      const int col = ((n&1)<<4) + lane16;
      #pragma unroll
      for (int i = 0; i < 4; ++i){
        if (co + i < Cout){
          float v = acc[mi][n][i] + (bias ? bias[co+i] : 0.f);
          out[(((size_t)(b*Cout + co + i)) << 10) + (row<<5) + col] = v;
          lsum += v; lsq += v*v;
        }
      }
    }
  }
  if (out_stats) red_atomic2(lsum, lsq, out_stats, b, t);
}

// ---------------------------------------------------------------------------
// Prep: fp32 [plane][64][1024] -> bf16 transposed [plane][1024][64] (outT),
// optional straight-cast copy (outC).
// ---------------------------------------------------------------------------
__global__ __launch_bounds__(256) void k_prep(const float* __restrict__ src,
                                              ushort* __restrict__ outC,
                                              ushort* __restrict__ outT)
{
  const int plane = blockIdx.y;
  const int p0 = blockIdx.x << 6;
  const float* sp = src + ((size_t)plane << 16);
  __shared__ __align__(16) float T[64][68];
  const int t = threadIdx.x, c = t >> 2, g = t & 3;
  #pragma unroll
  for (int i = 0; i < 4; ++i){
    float4 f = *(const float4*)(sp + ((size_t)c << 10) + p0 + (g << 4) + (i << 2));
    *(float4*)&T[c][(g << 4) + (i << 2)] = f;
    if (outC){
      uint2 pk2;
      pk2.x = (uint)f2b(f.x) | ((uint)f2b(f.y) << 16);
      pk2.y = (uint)f2b(f.z) | ((uint)f2b(f.w) << 16);
      *(uint2*)(outC + ((((size_t)plane << 6) + c) << 10) + p0 + (g << 4) + (i << 2)) = pk2;
    }
  }
  __syncthreads();
  const int p = t >> 2, c0 = (t & 3) << 4;
  uint w4[8];
  #pragma unroll
  for (int k = 0; k < 8; ++k){
    ushort lo = f2b(T[c0 + 2*k][p]);
    ushort hi = f2b(T[c0 + 2*k + 1][p]);
    w4[k] = (uint)lo | ((uint)hi << 16);
  }
  ushort* dst = outT + ((((size_t)plane << 10) + p0 + p) << 6) + c0;
  *(uint4*)(dst)     = *(uint4*)&w4[0];
  *(uint4*)(dst + 8) = *(uint4*)&w4[4];
}

// ---------------------------------------------------------------------------
// Gates
// ---------------------------------------------------------------------------
__global__ __launch_bounds__(256) void k_gates(
    const float* __restrict__ bufx, const float* __restrict__ bufh, const float* __restrict__ bufm,
    const float* __restrict__ lnxg, const float* __restrict__ lnxb,
    const float* __restrict__ lnhg, const float* __restrict__ lnhb,
    const float* __restrict__ lnmg, const float* __restrict__ lnmb,
    const float* __restrict__ m_t, const float* __restrict__ stats,
    float* __restrict__ ft, float* __restrict__ ig, float* __restrict__ osum,
    float* __restrict__ memo, float* __restrict__ out_m)
{
  const int idx = blockIdx.x*256 + threadIdx.x;
  const int b = idx >> 16, rem = idx & 65535;
  const int c = rem >> 10, p = rem & 1023;

  float mx = stats[b*2]      * (1.f/458752.f);
  float vx = stats[b*2+1]    * (1.f/458752.f) - mx*mx;  float rx = rsqrtf(vx + 1e-5f);
  float mh = stats[32+b*2]   * (1.f/262144.f);
  float vh = stats[32+b*2+1] * (1.f/262144.f) - mh*mh;  float rh = rsqrtf(vh + 1e-5f);
  float mm = stats[64+b*2]   * (1.f/196608.f);
  float vm = stats[64+b*2+1] * (1.f/196608.f) - mm*mm;  float rm = rsqrtf(vm + 1e-5f);

  auto LX = [&](int k){
    size_t ch = (size_t)k*64 + c; size_t gi = ((size_t)b*448 + ch)*1024 + p; size_t li = ch*1024 + p;
    return (bufx[gi] - mx)*rx*lnxg[li] + lnxb[li]; };
  auto LH = [&](int k){
    size_t ch = (size_t)k*64 + c; size_t gi = ((size_t)b*256 + ch)*1024 + p; size_t li = ch*1024 + p;
    return (bufh[gi] - mh)*rh*lnhg[li] + lnhb[li]; };
  auto LM = [&](int k){
    size_t ch = (size_t)k*64 + c; size_t gi = ((size_t)b*192 + ch)*1024 + p; size_t li = ch*1024 + p;
    return (bufm[gi] - mm)*rm*lnmg[li] + lnmb[li]; };

  float i_t = sigm(LX(0) + LH(0));
  float f_t = sigm(LX(1) + LH(1) + 1.f);
  float g_t = tanh_(LX(2) + LH(2));
  float i_p = sigm(LX(3) + LM(0));
  float f_p = sigm(LX(4) + LM(1) + 1.f);
  float g_p = tanh_(LX(5) + LM(2));
  float ox = LX(6), oh = LH(3);

  ft[idx]   = f_t;
  ig[idx]   = i_t * g_t;
  osum[idx] = ox + oh;
  float mn = f_p * m_t[idx] + i_p * g_p;
  out_m[idx] = mn;
  memo[((size_t)(b*128 + 64 + c) << 10) + p] = mn;
}

// ---------------------------------------------------------------------------
// Spatial attention via bf16 MFMA (fixed-shift softmax, additive num/den).
// ---------------------------------------------------------------------------
__global__ __launch_bounds__(256) void k_spat_mfma(
    const ushort* __restrict__ qT, const ushort* __restrict__ kvC, const ushort* __restrict__ kvT,
    const float* __restrict__ c_t, float* __restrict__ sp_raw, float* __restrict__ stats)
{
  const int p0 = blockIdx.x << 6, b = blockIdx.y;
  const int t = threadIdx.x, w = t >> 6, l = t & 63;
  const int lane16 = l & 15, quad = l >> 4;
  __shared__ __align__(16) ushort Kt[64][72];
  __shared__ __align__(16) ushort Kc[64][72];
  __shared__ __align__(16) ushort Eb[64][72];
  __shared__ __align__(16) float  XO[64][65];

  s8v qa0, qa1;
  {
    const ushort* qr = qT + ((((size_t)b << 10) + p0 + (w << 4) + lane16) << 6) + (quad << 3);
    qa0 = *(const s8v*)(qr);
    qa1 = *(const s8v*)(qr + 32);
  }
  f4v o0 = {0.f,0.f,0.f,0.f}, o1 = o0, o2 = o0, o3 = o0, dacc = o0;
  const short oneb = (short)0x3F80;
  const s8v ones = { oneb, oneb, oneb, oneb, oneb, oneb, oneb, oneb };

  const int r = t >> 2, g4 = (t & 3) << 4;
  for (int chunk = 0; chunk < 64; ++chunk){
    const int lidx = chunk >> 4, pk = (chunk & 15) << 6;
    __syncthreads();
    {
      const ushort* sc = kvC + ((((size_t)(b*4 + lidx) << 6) + r) << 10) + pk + g4;
      *(uint4*)&Kc[r][g4]     = *(const uint4*)(sc);
      *(uint4*)&Kc[r][g4 + 8] = *(const uint4*)(sc + 8);
      const ushort* st = kvT + ((((size_t)(b*4 + lidx) << 10) + pk + r) << 6) + g4;
      *(uint4*)&Kt[r][g4]     = *(const uint4*)(st);
      *(uint4*)&Kt[r][g4 + 8] = *(const uint4*)(st + 8);
    }
    __syncthreads();
    #pragma unroll
    for (int nt = 0; nt < 4; ++nt){
      const ushort* bt = &Kt[(nt << 4) + lane16][quad << 3];
      s8v b0 = *(const s8v*)(bt);
      s8v b1 = *(const s8v*)(bt + 32);
      f4v s = {0.f,0.f,0.f,0.f};
      s = __builtin_amdgcn_mfma_f32_16x16x32_bf16(qa0, b0, s, 0, 0, 0);
      s = __builtin_amdgcn_mfma_f32_16x16x32_bf16(qa1, b1, s, 0, 0, 0);
      #pragma unroll
      for (int i = 0; i < 4; ++i){
        float e = __expf(s[i] - 12.f);
        Eb[(w << 4) + (quad << 2) + i][(nt << 4) + lane16] = f2b(e);
      }
    }
    __syncthreads();
    #pragma unroll
    for (int ks = 0; ks < 2; ++ks){
      s8v ea = *(const s8v*)&Eb[(w << 4) + lane16][(ks << 5) + (quad << 3)];
      dacc = __builtin_amdgcn_mfma_f32_16x16x32_bf16(ea, ones, dacc, 0, 0, 0);
      s8v bc0 = *(const s8v*)&Kc[ 0 + lane16][(ks << 5) + (quad << 3)];
      s8v bc1 = *(const s8v*)&Kc[16 + lane16][(ks << 5) + (quad << 3)];
      s8v bc2 = *(const s8v*)&Kc[32 + lane16][(ks << 5) + (quad << 3)];
      s8v bc3 = *(const s8v*)&Kc[48 + lane16][(ks << 5) + (quad << 3)];
      o0 = __builtin_amdgcn_mfma_f32_16x16x32_bf16(ea, bc0, o0, 0, 0, 0);
      o1 = __builtin_amdgcn_mfma_f32_16x16x32_bf16(ea, bc1, o1, 0, 0, 0);
      o2 = __builtin_amdgcn_mfma_f32_16x16x32_bf16(ea, bc2, o2, 0, 0, 0);
      o3 = __builtin_amdgcn_mfma_f32_16x16x32_bf16(ea, bc3, o3, 0, 0, 0);
    }
  }
  {
    float inv0 = 1.f/dacc[0], inv1 = 1.f/dacc[1], inv2 = 1.f/dacc[2], inv3 = 1.f/dacc[3];
    const int pxl = (w << 4) + (quad << 2);
    XO[ 0 + lane16][pxl+0] = o0[0]*inv0; XO[ 0 + lane16][pxl+1] = o0[1]*inv1;
    XO[ 0 + lane16][pxl+2] = o0[2]*inv2; XO[ 0 + lane16][pxl+3] = o0[3]*inv3;
    XO[16 + lane16][pxl+0] = o1[0]*inv0; XO[16 + lane16][pxl+1] = o1[1]*inv1;
    XO[16 + lane16][pxl+2] = o1[2]*inv2; XO[16 + lane16][pxl+3] = o1[3]*inv3;
    XO[32 + lane16][pxl+0] = o2[0]*inv0; XO[32 + lane16][pxl+1] = o2[1]*inv1;
    XO[32 + lane16][pxl+2] = o2[2]*inv2; XO[32 + lane16][pxl+3] = o2[3]*inv3;
    XO[48 + lane16][pxl+0] = o3[0]*inv0; XO[48 + lane16][pxl+1] = o3[1]*inv1;
    XO[48 + lane16][pxl+2] = o3[2]*inv2; XO[48 + lane16][pxl+3] = o3[3]*inv3;
  }
  __syncthreads();
  {
    const int ch = t >> 2;
    float lsum = 0.f, lsq = 0.f;
    #pragma unroll
    for (int i = 0; i < 4; ++i){
      size_t gi = ((size_t)b << 16) + ((size_t)ch << 10) + p0 + g4 + (i << 2);
      float4 cv = *(const float4*)(c_t + gi);
      float4 ov;
      ov.x = cv.x + XO[ch][g4 + (i << 2) + 0];
      ov.y = cv.y + XO[ch][g4 + (i << 2) + 1];
      ov.z = cv.z + XO[ch][g4 + (i << 2) + 2];
      ov.w = cv.w + XO[ch][g4 + (i << 2) + 3];
      *(float4*)(sp_raw + gi) = ov;
      lsum += ov.x + ov.y + ov.z + ov.w;
      lsq  += ov.x*ov.x + ov.y*ov.y + ov.z*ov.z + ov.w*ov.w;
    }
    red_atomic2(lsum, lsq, stats, b, t);
  }
}

// ---------------------------------------------------------------------------
// Channel attention: logits GEMM, wave softmax, AV GEMM
// ---------------------------------------------------------------------------
__global__ __launch_bounds__(256) void k_chlog(
    const float* __restrict__ ft, const float* __restrict__ chist, float* __restrict__ lg)
{
  const int l = blockIdx.x, b = blockIdx.y, t = threadIdx.x;
  const int tc = t & 15, tk = t >> 4;
  __shared__ __align__(16) float Fs[64][68];
  __shared__ __align__(16) float Ks[64][68];
  float acc[4][4] = {};
  for (int pc = 0; pc < 16; ++pc){
    __syncthreads();
    {
      const int j = t & 63, c0 = t >> 6;
      const float* fp = ft + ((size_t)b << 16) + (pc << 6) + j;
      const float* kp = chist + (((size_t)(b*4 + l)) << 16) + (pc << 6) + j;
      #pragma unroll
      for (int c = c0; c < 64; c += 4){ Fs[c][j] = fp[(size_t)c << 10]; Ks[c][j] = kp[(size_t)c << 10]; }
    }
    __syncthreads();
    #pragma unroll 4
    for (int p = 0; p < 64; p += 4){
      float fv[4][4], kv[4][4];
      #pragma unroll
      for (int i = 0; i < 4; ++i) *(float4*)fv[i] = *(const float4*)&Fs[4*tc+i][p];
      #pragma unroll
      for (int j = 0; j < 4; ++j) *(float4*)kv[j] = *(const float4*)&Ks[4*tk+j][p];
      #pragma unroll
      for (int i = 0; i < 4; ++i)
        #pragma unroll
        for (int j = 0; j < 4; ++j)
          #pragma unroll
          for (int k = 0; k < 4; ++k)
            acc[i][j] = fmaf(fv[i][k], kv[j][k], acc[i][j]);
    }
  }
  #pragma unroll
  for (int i = 0; i < 4; ++i)
    #pragma unroll
    for (int j = 0; j < 4; ++j)
      lg[((size_t)(b*64 + 4*tc + i) << 8) + (l << 6) + 4*tk + j] = acc[i][j];
}

__global__ __launch_bounds__(256) void k_chsm(float* __restrict__ a)
{
  const int row  = blockIdx.x*4 + (threadIdx.x >> 6);
  const int lane = threadIdx.x & 63;
  float* rp = a + ((size_t)row << 8);
  float v0 = rp[lane], v1 = rp[lane+64], v2 = rp[lane+128], v3 = rp[lane+192];
  float mx = fmaxf(fmaxf(v0, v1), fmaxf(v2, v3));
  #pragma unroll
  for (int m = 32; m; m >>= 1) mx = fmaxf(mx, __shfl_xor(mx, m));
  v0 = __expf(v0 - mx); v1 = __expf(v1 - mx); v2 = __expf(v2 - mx); v3 = __expf(v3 - mx);
  float s = v0 + v1 + v2 + v3;
  #pragma unroll
  for (int m = 32; m; m >>= 1) s += __shfl_xor(s, m);
  float inv = 1.f / s;
  rp[lane] = v0*inv; rp[lane+64] = v1*inv; rp[lane+128] = v2*inv; rp[lane+192] = v3*inv;
}

__global__ __launch_bounds__(256) void k_chout(
    const float* __restrict__ a, const float* __restrict__ chist,
    const float* __restrict__ c_t, float* __restrict__ ch_raw, float* __restrict__ stats)
{
  const int p0 = blockIdx.x << 6, b = blockIdx.y, t = threadIdx.x;
  const int tc = t & 15, tp = t >> 4;
  __shared__ __align__(16) float As[64][68];
  __shared__ __align__(16) float Ks[64][68];
  float acc[4][4] = {};
  for (int h = 0; h < 4; ++h){
    __syncthreads();
    {
      const int j = t & 63, c0 = t >> 6;
      const float* ap = a + ((size_t)b << 14) + (h << 6) + j;
      #pragma unroll
      for (int c = c0; c < 64; c += 4) As[j][c] = ap[(size_t)c << 8];
      const int p = t & 63, j0 = t >> 6;
      const float* kp = chist + (((size_t)(b*4 + h)) << 16) + p0 + p;
      #pragma unroll
      for (int jj = j0; jj < 64; jj += 4) Ks[jj][p] = kp[(size_t)jj << 10];
    }
    __syncthreads();
    #pragma unroll 4
    for (int k = 0; k < 64; k += 4){
      float av[4][4], kv[4][4];
      #pragma unroll
      for (int j = 0; j < 4; ++j){ *(float4*)av[j] = *(const float4*)&As[k+j][4*tc];
                                   *(float4*)kv[j] = *(const float4*)&Ks[k+j][4*tp]; }
      #pragma unroll
      for (int ci = 0; ci < 4; ++ci)
        #pragma unroll
        for (int pi = 0; pi < 4; ++pi)
          #pragma unroll
          for (int j = 0; j < 4; ++j)
            acc[ci][pi] = fmaf(av[j][ci], kv[j][pi], acc[ci][pi]);
    }
  }
  float lsum = 0.f, lsq = 0.f;
  #pragma unroll
  for (int ci = 0; ci < 4; ++ci)
    #pragma unroll
    for (int pi = 0; pi < 4; ++pi){
      size_t gi = ((size_t)b << 16) + ((size_t)(4*tc + ci) << 10) + p0 + 4*tp + pi;
      float v = c_t[gi] + acc[ci][pi];
      ch_raw[gi] = v;
      lsum += v; lsq += v*v;
    }
  red_atomic2(lsum, lsq, stats, b, t);
}

// ---------------------------------------------------------------------------
// LN+relu both attention branches, 1x1 convs, sum, 1x1 attn_w, c_new
// ---------------------------------------------------------------------------
__global__ __launch_bounds__(256) void k_attnfinal(
    const float* __restrict__ samid, const float* __restrict__ camid,
    const float* __restrict__ stats_sa, const float* __restrict__ stats_ca,
    const float* __restrict__ salng, const float* __restrict__ salnb,
    const float* __restrict__ calng, const float* __restrict__ calnb,
    const float* __restrict__ wsa2, const float* __restrict__ wca2,
    const float* __restrict__ cab2, const float* __restrict__ wat,
    const float* __restrict__ ig, float* __restrict__ out_c, float* __restrict__ memo)
{
  const int p0 = blockIdx.x << 6, b = blockIdx.y, t = threadIdx.x;
  const int tc = t & 15, tp = t >> 4;
  __shared__ __align__(16) float R[64][68];
  __shared__ __align__(16) float Wl[64][68];
  __shared__ __align__(16) float Ms[64][68];
  const float invN = 1.f/65536.f;
  float acc[4][4] = {};
  #pragma unroll
  for (int pass = 0; pass < 2; ++pass){
    const float* mid = pass ? camid : samid;
    const float* st  = pass ? stats_ca : stats_sa;
    const float* g   = pass ? calng : salng;
    const float* bb  = pass ? calnb : salnb;
    const float* w   = pass ? wca2  : wsa2;
    float mean = st[b*2]*invN;
    float var  = st[b*2+1]*invN - mean*mean;
    float rstd = rsqrtf(var + 1e-5f);
    __syncthreads();
    {
      const int j = t & 63, c0 = t >> 6;
      for (int ci = c0; ci < 64; ci += 4){
        size_t gi = ((size_t)b << 16) + ((size_t)ci << 10) + p0 + j;
        size_t li = ((size_t)ci << 10) + p0 + j;
        float v = (mid[gi] - mean)*rstd*g[li] + bb[li];
        R[ci][j] = fmaxf(v, 0.f);
      }
      const int ci2 = t & 63, c20 = t >> 6;
      for (int c2 = c20; c2 < 64; c2 += 4) Wl[ci2][c2] = w[((size_t)c2 << 6) + ci2];
    }
    __syncthreads();
    for (int ci = 0; ci < 64; ++ci){
      float wv[4], rv[4];
      *(float4*)wv = *(const float4*)&Wl[ci][4*tc];
      *(float4*)rv = *(const float4*)&R[ci][4*tp];
      #pragma unroll
      for (int i = 0; i < 4; ++i)
        #pragma unroll
        for (int j = 0; j < 4; ++j)
          acc[i][j] = fmaf(wv[i], rv[j], acc[i][j]);
    }
  }
  {
    float b2[4];
    #pragma unroll
    for (int i = 0; i < 4; ++i) b2[i] = cab2[4*tc + i];
    #pragma unroll
    for (int i = 0; i < 4; ++i)
      #pragma unroll
      for (int j = 0; j < 4; ++j)
        Ms[4*tc+i][4*tp+j] = acc[i][j] + b2[i];
  }
  __syncthreads();
  {
    const int ci2 = t & 63, c20 = t >> 6;
    for (int c2 = c20; c2 < 64; c2 += 4) Wl[ci2][c2] = wat[((size_t)c2 << 6) + ci2];
  }
  __syncthreads();
  float acc2[4][4] = {};
  for (int c2 = 0; c2 < 64; ++c2){
    float wv[4], mv[4];
    *(float4*)wv = *(const float4*)&Wl[c2][4*tc];
    *(float4*)mv = *(const float4*)&Ms[c2][4*tp];
    #pragma unroll
    for (int i = 0; i < 4; ++i)
      #pragma unroll
      for (int j = 0; j < 4; ++j)
        acc2[i][j] = fmaf(wv[i], mv[j], acc2[i][j]);
  }
  #pragma unroll
  for (int i = 0; i < 4; ++i)
    #pragma unroll
    for (int j = 0; j < 4; ++j){
      size_t gi = ((size_t)b << 16) + ((size_t)(4*tc + i) << 10) + p0 + 4*tp + j;
      float v = acc2[i][j] + ig[gi];
      out_c[gi] = v;
      memo[((size_t)(b*128 + 4*tc + i) << 10) + p0 + 4*tp + j] = v;
    }
}

// ---------------------------------------------------------------------------
__global__ __launch_bounds__(256) void k_final(
    const float* __restrict__ memo, const float* __restrict__ wlast,
    const float* __restrict__ bufo, const float* __restrict__ osum,
    const float* __restrict__ stats_o, const float* __restrict__ lnog, const float* __restrict__ lnob,
    float* __restrict__ out_h)
{
  const int p0 = blockIdx.x << 6, b = blockIdx.y, t = threadIdx.x;
  const int tc = t & 15, tp = t >> 4;
  __shared__ __align__(16) float Msh[64][68];
  __shared__ __align__(16) float Wt[64][68];
  float acc[4][4] = {};
  #pragma unroll
  for (int half = 0; half < 2; ++half){
    __syncthreads();
    {
      const int j = t & 63, c0 = t >> 6;
      for (int ci = c0; ci < 64; ci += 4)
        Msh[ci][j] = memo[((size_t)(b*128 + half*64 + ci) << 10) + p0 + j];
      const int ci2 = t & 63, co0 = t >> 6;
      for (int co = co0; co < 64; co += 4) Wt[ci2][co] = wlast[((size_t)co << 7) + half*64 + ci2];
    }
    __syncthreads();
    for (int ci = 0; ci < 64; ++ci){
      float wv[4], mv[4];
      *(float4*)wv = *(const float4*)&Wt[ci][4*tc];
      *(float4*)mv = *(const float4*)&Msh[ci][4*tp];
      #pragma unroll
      for (int i = 0; i < 4; ++i)
        #pragma unroll
        for (int j = 0; j < 4; ++j)
          acc[i][j] = fmaf(wv[i], mv[j], acc[i][j]);
    }
  }
  float mean = stats_o[b*2]*(1.f/65536.f);
  float var  = stats_o[b*2+1]*(1.f/65536.f) - mean*mean;
  float rstd = rsqrtf(var + 1e-5f);
  #pragma unroll
  for (int i = 0; i < 4; ++i)
    #pragma unroll
    for (int j = 0; j < 4; ++j){
      const int co = 4*tc + i, p = p0 + 4*tp + j;
      size_t gi = ((size_t)b << 16) + ((size_t)co << 10) + p;
      size_t li = ((size_t)co << 10) + p;
      float lno = (bufo[gi] - mean)*rstd*lnog[li] + lnob[li];
      float o = sigm(osum[gi] + lno);
      out_h[gi] = o * tanh_(acc[i][j]);
    }
}

// ---------------------------------------------------------------------------
extern "C" void kernel_launch(void* const* d_in, const int* in_sizes, int n_in,
                              void* d_out, int out_size, void* d_ws, size_t ws_size,
                              hipStream_t stream)
{
  const float* x_t   = (const float*)d_in[0];
  const float* h_t   = (const float*)d_in[1];
  const float* c_t   = (const float*)d_in[2];
  const float* chist = (const float*)d_in[3];
  const float* m_t   = (const float*)d_in[4];
  const float* w_x   = (const float*)d_in[5];
  const float* lnxg  = (const float*)d_in[6];
  const float* lnxb  = (const float*)d_in[7];
  const float* w_h   = (const float*)d_in[8];
  const float* lnhg  = (const float*)d_in[9];
  const float* lnhb  = (const float*)d_in[10];
  const float* w_m   = (const float*)d_in[11];
  const float* lnmg  = (const float*)d_in[12];
  const float* lnmb  = (const float*)d_in[13];
  const float* w_o   = (const float*)d_in[14];
  const float* lnog  = (const float*)d_in[15];
  const float* lnob  = (const float*)d_in[16];
  const float* w_last= (const float*)d_in[17];
  const float* sng   = (const float*)d_in[18];
  const float* snb   = (const float*)d_in[19];
  const float* cng   = (const float*)d_in[20];
  const float* cnb   = (const float*)d_in[21];
  const float* ca_w1 = (const float*)d_in[22];
  const float* ca_b1 = (const float*)d_in[23];
  const float* calng = (const float*)d_in[24];
  const float* calnb = (const float*)d_in[25];
  const float* ca_w2 = (const float*)d_in[26];
  const float* ca_b2 = (const float*)d_in[27];
  const float* sa_w1 = (const float*)d_in[28];
  const float* salng = (const float*)d_in[29];
  const float* salnb = (const float*)d_in[30];
  const float* sa_w2 = (const float*)d_in[31];
  const float* attn_w= (const float*)d_in[32];

  float* out = (float*)d_out;
  float* ws  = (float*)d_ws;

  // workspace layout (floats). Total = 1024 + 19*N1 ~= 79.7 MB
  float* stats = ws;                        // 8 groups x 16 batches x {sum,sumsq}
  float* bufx  = ws + 1024;                 // 7*N1 raw conv_x
  float* bufh  = bufx + 7*(size_t)N1;       // 4*N1
  float* bufm  = bufh + 4*(size_t)N1;       // 3*N1
  float* ft    = bufm + 3*(size_t)N1;       // N1
  float* ig    = ft   + (size_t)N1;         // N1
  float* osum  = ig   + (size_t)N1;         // N1
  float* memo  = osum + (size_t)N1;         // 2*N1
  // aliases valid AFTER k_gates consumed bufx/h/m:
  float* sp    = bufx;                      // N1
  float* ch    = bufx + (size_t)N1;         // N1
  float* samid = bufx + 2*(size_t)N1;       // N1
  float* camid = bufx + 3*(size_t)N1;       // N1
  float* bufo  = bufx + 4*(size_t)N1;       // N1
  float* chl   = bufx + 5*(size_t)N1;       // channel-attn logits (1 MB)
  ushort* kvC  = (ushort*)bufh;             // 4M bf16 (8 MB)
  ushort* kvT  = kvC + 4*(size_t)N1;        // 4M bf16 (8 MB)
  ushort* qT   = (ushort*)bufm;             // 1M bf16 (2 MB)

  // bf16 weights: xhm pack lives in ft region (free until k_gates writes it)
  ushort* wbx = (ushort*)ft;                // 716800
  ushort* wbh = wbx + 716800;               // 409600
  ushort* wbm = wbh + 409600;               // 307200   (total 2.87 MB < 4 MB)
  // o/sa/ca pack lives after chl in bufx region (free after k_gates)
  ushort* wbo  = (ushort*)(chl + 262144);   // 204800
  ushort* wbsa = wbo + 204800;              // 102400
  ushort* wbca = wbsa + 102400;             // 102400  (0.8 MB < 7 MB free)

  float* out_h = out;
  float* out_c = out + (size_t)N1;
  float* out_m = out + 2*(size_t)N1;

  k_zero<<<dim3(1), dim3(256), 0, stream>>>(stats);

  // bf16 weight prep for x/h/m convs
  k_wprep3<<<dim3(5600), dim3(256), 0, stream>>>(
      w_x, wbx, 448, 64, 716800,
      w_h, wbh, 256, 64, 409600,
      w_m, wbm, 192, 64, 307200);

  // big convs (MFMA) + LN stats   (stats slots: x=0, h=32, m=64)
  k_conv5m<8><<<dim3(16,16), dim3(256), 0, stream>>>(x_t, 64, wbx, nullptr, bufx, 448, stats+0,
                                                     nullptr, 0.f, nullptr, nullptr);
  k_conv5m<8><<<dim3(8,16), dim3(256), 0, stream>>>(h_t, 64, wbh, nullptr, bufh, 256, stats+32,
                                                     nullptr, 0.f, nullptr, nullptr);
  k_conv5m<8><<<dim3(8,16), dim3(256), 0, stream>>>(m_t, 64, wbm, nullptr, bufm, 192, stats+64,
                                                     nullptr, 0.f, nullptr, nullptr);

  k_gates<<<dim3(4096), dim3(256), 0, stream>>>(bufx, bufh, bufm, lnxg, lnxb, lnhg, lnhb,
                                                lnmg, lnmb, m_t, stats,
                                                ft, ig, osum, memo, out_m);

  // bf16 weight prep for o/sa/ca convs (regions free only after k_gates)
  k_wprep3<<<dim3(1600), dim3(256), 0, stream>>>(
      w_o,   wbo,  64, 128, 204800,
      sa_w1, wbsa, 64,  64, 102400,
      ca_w1, wbca, 64,  64, 102400);

  // bf16 prep for spatial attention
  k_prep<<<dim3(16,64), dim3(256), 0, stream>>>(chist, kvC, kvT);
  k_prep<<<dim3(16,16), dim3(256), 0, stream>>>(ft, nullptr, qT);

  // attention branches  (stats: sp=96, ch=128)
  k_spat_mfma<<<dim3(16,16), dim3(256), 0, stream>>>(qT, kvC, kvT, c_t, sp, stats+96);
  k_chlog<<<dim3(4,16),  dim3(256), 0, stream>>>(ft, chist, chl);
  k_chsm <<<dim3(256),   dim3(256), 0, stream>>>(chl);
  k_chout<<<dim3(16,16), dim3(256), 0, stream>>>(chl, chist, c_t, ch, stats+128);

  // 5x5 MFMA convs over LN(sp)/LN(ch)  (stats: sa=160, ca=192)
  k_conv5m<4><<<dim3(4,16), dim3(256), 0, stream>>>(sp, 64, wbsa, nullptr, samid, 64, stats+160,
                                                    stats+96, 1.f/65536.f, sng, snb);
  k_conv5m<4><<<dim3(4,16), dim3(256), 0, stream>>>(ch, 64, wbca, ca_b1, camid, 64, stats+192,
                                                    stats+128, 1.f/65536.f, cng, cnb);

  k_attnfinal<<<dim3(16,16), dim3(256), 0, stream>>>(samid, camid, stats+160, stats+192,
                                                     salng, salnb, calng, calnb,
                                                     sa_w2, ca_w2, ca_b2, attn_w,
                                                     ig, out_c, memo);

  // conv_o over mem (Cin=128)  (stats: o=224)
  k_conv5m<4><<<dim3(4,16), dim3(256), 0, stream>>>(memo, 128, wbo, nullptr, bufo, 64, stats+224,
                                                    nullptr, 0.f, nullptr, nullptr);

  k_final<<<dim3(16,16), dim3(256), 0, stream>>>(memo, w_last, bufo, osum, stats+224,
                                                 lnog, lnob, out_h);
}

// Round 4
// 685.652 us; speedup vs baseline: 4.1313x; 1.5200x over previous
//
#include <hip/hip_runtime.h>
#include <hip/hip_bf16.h>

#define N1 (1u << 20)   // B*NH*HW = 16*64*1024

typedef __attribute__((ext_vector_type(8))) short s8v;
typedef __attribute__((ext_vector_type(4))) float f4v;

static __device__ __forceinline__ float sigm(float x){ return 1.f/(1.f + __expf(-x)); }
static __device__ __forceinline__ float tanh_(float x){ return 1.f - 2.f/(__expf(2.f*x) + 1.f); }

static __device__ __forceinline__ ushort f2b(float f){
  union { float f; uint u; } x; x.f = f;
  uint r = x.u + 0x7FFFu + ((x.u >> 16) & 1u);
  return (ushort)(r >> 16);
}

static __device__ __forceinline__ void red_atomic2(float s, float q, float* d, int b, int t){
  #pragma unroll
  for (int m = 32; m; m >>= 1){ s += __shfl_xor(s, m); q += __shfl_xor(q, m); }
  if ((t & 63) == 0){ atomicAdd(&d[b*2], s); atomicAdd(&d[b*2+1], q); }
}

__global__ void k_zero(float* __restrict__ p){ p[threadIdx.x] = 0.f; }

// ---------------------------------------------------------------------------
// Weight prep: fp32 [Co][Ci][5][5] -> bf16 [tap][Co][Ci], three convs fused.
// ---------------------------------------------------------------------------
__global__ __launch_bounds__(256) void k_wprep3(
    const float* __restrict__ sA, ushort* __restrict__ dA, int CoA, int CiA, int nA,
    const float* __restrict__ sB, ushort* __restrict__ dB, int CoB, int CiB, int nB,
    const float* __restrict__ sC, ushort* __restrict__ dC, int CoC, int CiC, int nC)
{
  int idx = blockIdx.x*256 + threadIdx.x;
  const float* s; ushort* d; int Co, Ci;
  if (idx < nA){ s=sA; d=dA; Co=CoA; Ci=CiA; }
  else if ((idx -= nA) < nB){ s=sB; d=dB; Co=CoB; Ci=CiB; }
  else if ((idx -= nB) < nC){ s=sC; d=dC; Co=CoC; Ci=CiC; }
  else return;
  int ci = idx % Ci; int r = idx / Ci; int co = r % Co; int tap = r / Co;
  d[idx] = f2b(s[((size_t)(co*Ci + ci))*25 + tap]);
}

// ---------------------------------------------------------------------------
// MFMA 5x5 SAME conv. Block: MT*16 co x 4 rows (128 px). 4 waves, wave w owns
// output row r0+w (2 n-tiles of 16 px). Weights staged per dy-row (5 taps) in
// double-buffered LDS, loads register-prefetched a full group ahead.
// One barrier per dy-group (5 per ci-chunk, not 25).
// ---------------------------------------------------------------------------
template<int MT>
__global__ __launch_bounds__(256, 2) void k_conv5g(
    const float* __restrict__ in, int Cin,
    const ushort* __restrict__ wB, const float* __restrict__ bias,
    float* __restrict__ out, int Cout,
    float* __restrict__ out_stats,
    const float* __restrict__ in_stats, float in_invN,
    const float* __restrict__ in_g, const float* __restrict__ in_b)
{
  const int b = blockIdx.y;
  const int cog = blockIdx.x >> 3, pxblk = blockIdx.x & 7;
  const int co0 = cog * (MT*16);
  const int r0 = pxblk << 2;
  const int t = threadIdx.x, w = t >> 6, l = t & 63;
  const int lane16 = l & 15, quad = l >> 4;

  __shared__ __align__(16) ushort S[4][8][36][8];        // [ci-quad][row][col][8ci]
  __shared__ __align__(16) ushort W[2][4][5][MT*16][8];  // [buf][ci-quad][dx][co][8ci]

  constexpr int NW  = 5*MT*16*4;           // uint4 elems per weight group
  constexpr int ITW = (NW + 255) / 256;    // per-thread iterations

  f4v acc[MT][2];
  #pragma unroll
  for (int mi = 0; mi < MT; ++mi){ acc[mi][0] = (f4v){0.f,0.f,0.f,0.f}; acc[mi][1] = (f4v){0.f,0.f,0.f,0.f}; }

  float mean = 0.f, rstd = 0.f;
  if (in_stats){
    float s0 = in_stats[b*2], s1 = in_stats[b*2+1];
    mean = s0 * in_invN;
    rstd = rsqrtf(s1 * in_invN - mean*mean + 1e-5f);
  }

  const int ncc = Cin >> 5;
  for (int cc = 0; cc < ncc; ++cc){
    __syncthreads();
    // ---- stage input stripe: rows r0-2..r0+5, cols -2..33, 32 ci ----
    for (int idx = t; idx < 288; idx += 256){
      const int row = idx / 36, col = idx - row*36;
      const int ir = r0 - 2 + row, ic = col - 2;
      uint4 pk[4] = {make_uint4(0,0,0,0),make_uint4(0,0,0,0),make_uint4(0,0,0,0),make_uint4(0,0,0,0)};
      if ((unsigned)ir < 32u && (unsigned)ic < 32u){
        const int pix = (ir << 5) + ic;
        const float* bp = in + (((size_t)(b*Cin + (cc<<5))) << 10) + pix;
        #pragma unroll
        for (int q = 0; q < 4; ++q){
          uint hw[4];
          #pragma unroll
          for (int jj = 0; jj < 4; ++jj){
            const int c0 = q*8 + jj*2;
            float v0 = bp[(size_t)c0 << 10];
            float v1 = bp[(size_t)(c0+1) << 10];
            if (in_g){
              const size_t li0 = (((size_t)((cc<<5)+c0)) << 10) + pix;
              v0 = (v0 - mean)*rstd*in_g[li0] + in_b[li0];
              v1 = (v1 - mean)*rstd*in_g[li0+1024] + in_b[li0+1024];
            }
            hw[jj] = (uint)f2b(v0) | ((uint)f2b(v1) << 16);
          }
          pk[q] = make_uint4(hw[0], hw[1], hw[2], hw[3]);
        }
      }
      #pragma unroll
      for (int q = 0; q < 4; ++q) *(uint4*)&S[q][row][col][0] = pk[q];
    }
    // ---- stage weight group dy=0 into buf 0 ----
    #pragma unroll
    for (int it = 0; it < ITW; ++it){
      const int idx = t + it*256;
      if (ITW*256 == NW || idx < NW){
        const int q = idx & 3, r = idx >> 2;
        const int co = r & (MT*16 - 1), dx = r / (MT*16);
        uint4 wv = *(const uint4*)(wB + ((size_t)(dx*Cout + co0+co))*Cin + (cc<<5) + (q<<3));
        *(uint4*)&W[0][q][dx][co][0] = wv;
      }
    }
    __syncthreads();
    for (int dy = 0; dy < 5; ++dy){
      // prefetch next dy-group into regs (loads issue now, stores after compute)
      uint4 wreg[ITW];
      if (dy < 4){
        #pragma unroll
        for (int it = 0; it < ITW; ++it){
          const int idx = t + it*256;
          if (ITW*256 == NW || idx < NW){
            const int q = idx & 3, r = idx >> 2;
            const int co = r & (MT*16 - 1), dx = r / (MT*16);
            wreg[it] = *(const uint4*)(wB + ((size_t)(((dy+1)*5+dx)*Cout + co0+co))*Cin + (cc<<5) + (q<<3));
          }
        }
      }
      const int srow = w + dy;
      #pragma unroll
      for (int dx = 0; dx < 5; ++dx){
        s8v a[MT];
        #pragma unroll
        for (int mi = 0; mi < MT; ++mi)
          a[mi] = *(const s8v*)&W[dy & 1][quad][dx][mi*16 + lane16][0];
        #pragma unroll
        for (int n = 0; n < 2; ++n){
          s8v bb = *(const s8v*)&S[quad][srow][(n<<4) + lane16 + dx][0];
          #pragma unroll
          for (int mi = 0; mi < MT; ++mi)
            acc[mi][n] = __builtin_amdgcn_mfma_f32_16x16x32_bf16(a[mi], bb, acc[mi][n], 0, 0, 0);
        }
      }
      if (dy < 4){
        #pragma unroll
        for (int it = 0; it < ITW; ++it){
          const int idx = t + it*256;
          if (ITW*256 == NW || idx < NW){
            const int q = idx & 3, r = idx >> 2;
            const int co = r & (MT*16 - 1), dx = r / (MT*16);
            *(uint4*)&W[(dy+1) & 1][q][dx][co][0] = wreg[it];
          }
        }
      }
      __syncthreads();
    }
  }
  // ---- epilogue ----
  float lsum = 0.f, lsq = 0.f;
  const int row = r0 + w;
  #pragma unroll
  for (int mi = 0; mi < MT; ++mi){
    const int co = co0 + mi*16 + (quad<<2);
    #pragma unroll
    for (int n = 0; n < 2; ++n){
      const int col = (n<<4) + lane16;
      #pragma unroll
      for (int i = 0; i < 4; ++i){
        float v = acc[mi][n][i] + (bias ? bias[co+i] : 0.f);
        out[(((size_t)(b*Cout + co + i)) << 10) + (row<<5) + col] = v;
        lsum += v; lsq += v*v;
      }
    }
  }
  if (out_stats) red_atomic2(lsum, lsq, out_stats, b, t);
}

// ---------------------------------------------------------------------------
// Prep: fp32 [plane][64][1024] -> bf16 transposed [plane][1024][64] (outT),
// optional straight-cast copy (outC).
// ---------------------------------------------------------------------------
__global__ __launch_bounds__(256) void k_prep(const float* __restrict__ src,
                                              ushort* __restrict__ outC,
                                              ushort* __restrict__ outT)
{
  const int plane = blockIdx.y;
  const int p0 = blockIdx.x << 6;
  const float* sp = src + ((size_t)plane << 16);
  __shared__ __align__(16) float T[64][68];
  const int t = threadIdx.x, c = t >> 2, g = t & 3;
  #pragma unroll
  for (int i = 0; i < 4; ++i){
    float4 f = *(const float4*)(sp + ((size_t)c << 10) + p0 + (g << 4) + (i << 2));
    *(float4*)&T[c][(g << 4) + (i << 2)] = f;
    if (outC){
      uint2 pk2;
      pk2.x = (uint)f2b(f.x) | ((uint)f2b(f.y) << 16);
      pk2.y = (uint)f2b(f.z) | ((uint)f2b(f.w) << 16);
      *(uint2*)(outC + ((((size_t)plane << 6) + c) << 10) + p0 + (g << 4) + (i << 2)) = pk2;
    }
  }
  __syncthreads();
  const int p = t >> 2, c0 = (t & 3) << 4;
  uint w4[8];
  #pragma unroll
  for (int k = 0; k < 8; ++k){
    ushort lo = f2b(T[c0 + 2*k][p]);
    ushort hi = f2b(T[c0 + 2*k + 1][p]);
    w4[k] = (uint)lo | ((uint)hi << 16);
  }
  ushort* dst = outT + ((((size_t)plane << 10) + p0 + p) << 6) + c0;
  *(uint4*)(dst)     = *(uint4*)&w4[0];
  *(uint4*)(dst + 8) = *(uint4*)&w4[4];
}

// ---------------------------------------------------------------------------
// Gates
// ---------------------------------------------------------------------------
__global__ __launch_bounds__(256) void k_gates(
    const float* __restrict__ bufx, const float* __restrict__ bufh, const float* __restrict__ bufm,
    const float* __restrict__ lnxg, const float* __restrict__ lnxb,
    const float* __restrict__ lnhg, const float* __restrict__ lnhb,
    const float* __restrict__ lnmg, const float* __restrict__ lnmb,
    const float* __restrict__ m_t, const float* __restrict__ stats,
    float* __restrict__ ft, float* __restrict__ ig, float* __restrict__ osum,
    float* __restrict__ memo, float* __restrict__ out_m)
{
  const int idx = blockIdx.x*256 + threadIdx.x;
  const int b = idx >> 16, rem = idx & 65535;
  const int c = rem >> 10, p = rem & 1023;

  float mx = stats[b*2]      * (1.f/458752.f);
  float vx = stats[b*2+1]    * (1.f/458752.f) - mx*mx;  float rx = rsqrtf(vx + 1e-5f);
  float mh = stats[32+b*2]   * (1.f/262144.f);
  float vh = stats[32+b*2+1] * (1.f/262144.f) - mh*mh;  float rh = rsqrtf(vh + 1e-5f);
  float mm = stats[64+b*2]   * (1.f/196608.f);
  float vm = stats[64+b*2+1] * (1.f/196608.f) - mm*mm;  float rm = rsqrtf(vm + 1e-5f);

  auto LX = [&](int k){
    size_t ch = (size_t)k*64 + c; size_t gi = ((size_t)b*448 + ch)*1024 + p; size_t li = ch*1024 + p;
    return (bufx[gi] - mx)*rx*lnxg[li] + lnxb[li]; };
  auto LH = [&](int k){
    size_t ch = (size_t)k*64 + c; size_t gi = ((size_t)b*256 + ch)*1024 + p; size_t li = ch*1024 + p;
    return (bufh[gi] - mh)*rh*lnhg[li] + lnhb[li]; };
  auto LM = [&](int k){
    size_t ch = (size_t)k*64 + c; size_t gi = ((size_t)b*192 + ch)*1024 + p; size_t li = ch*1024 + p;
    return (bufm[gi] - mm)*rm*lnmg[li] + lnmb[li]; };

  float i_t = sigm(LX(0) + LH(0));
  float f_t = sigm(LX(1) + LH(1) + 1.f);
  float g_t = tanh_(LX(2) + LH(2));
  float i_p = sigm(LX(3) + LM(0));
  float f_p = sigm(LX(4) + LM(1) + 1.f);
  float g_p = tanh_(LX(5) + LM(2));
  float ox = LX(6), oh = LH(3);

  ft[idx]   = f_t;
  ig[idx]   = i_t * g_t;
  osum[idx] = ox + oh;
  float mn = f_p * m_t[idx] + i_p * g_p;
  out_m[idx] = mn;
  memo[((size_t)(b*128 + 64 + c) << 10) + p] = mn;
}

// ---------------------------------------------------------------------------
// Spatial attention via bf16 MFMA (fixed-shift softmax, additive num/den).
// ---------------------------------------------------------------------------
__global__ __launch_bounds__(256) void k_spat_mfma(
    const ushort* __restrict__ qT, const ushort* __restrict__ kvC, const ushort* __restrict__ kvT,
    const float* __restrict__ c_t, float* __restrict__ sp_raw, float* __restrict__ stats)
{
  const int p0 = blockIdx.x << 6, b = blockIdx.y;
  const int t = threadIdx.x, w = t >> 6, l = t & 63;
  const int lane16 = l & 15, quad = l >> 4;
  __shared__ __align__(16) ushort Kt[64][72];
  __shared__ __align__(16) ushort Kc[64][72];
  __shared__ __align__(16) ushort Eb[64][72];
  __shared__ __align__(16) float  XO[64][65];

  s8v qa0, qa1;
  {
    const ushort* qr = qT + ((((size_t)b << 10) + p0 + (w << 4) + lane16) << 6) + (quad << 3);
    qa0 = *(const s8v*)(qr);
    qa1 = *(const s8v*)(qr + 32);
  }
  f4v o0 = {0.f,0.f,0.f,0.f}, o1 = o0, o2 = o0, o3 = o0, dacc = o0;
  const short oneb = (short)0x3F80;
  const s8v ones = { oneb, oneb, oneb, oneb, oneb, oneb, oneb, oneb };

  const int r = t >> 2, g4 = (t & 3) << 4;
  for (int chunk = 0; chunk < 64; ++chunk){
    const int lidx = chunk >> 4, pk = (chunk & 15) << 6;
    __syncthreads();
    {
      const ushort* sc = kvC + ((((size_t)(b*4 + lidx) << 6) + r) << 10) + pk + g4;
      *(uint4*)&Kc[r][g4]     = *(const uint4*)(sc);
      *(uint4*)&Kc[r][g4 + 8] = *(const uint4*)(sc + 8);
      const ushort* st = kvT + ((((size_t)(b*4 + lidx) << 10) + pk + r) << 6) + g4;
      *(uint4*)&Kt[r][g4]     = *(const uint4*)(st);
      *(uint4*)&Kt[r][g4 + 8] = *(const uint4*)(st + 8);
    }
    __syncthreads();
    #pragma unroll
    for (int nt = 0; nt < 4; ++nt){
      const ushort* bt = &Kt[(nt << 4) + lane16][quad << 3];
      s8v b0 = *(const s8v*)(bt);
      s8v b1 = *(const s8v*)(bt + 32);
      f4v s = {0.f,0.f,0.f,0.f};
      s = __builtin_amdgcn_mfma_f32_16x16x32_bf16(qa0, b0, s, 0, 0, 0);
      s = __builtin_amdgcn_mfma_f32_16x16x32_bf16(qa1, b1, s, 0, 0, 0);
      #pragma unroll
      for (int i = 0; i < 4; ++i){
        float e = __expf(s[i] - 12.f);
        Eb[(w << 4) + (quad << 2) + i][(nt << 4) + lane16] = f2b(e);
      }
    }
    __syncthreads();
    #pragma unroll
    for (int ks = 0; ks < 2; ++ks){
      s8v ea = *(const s8v*)&Eb[(w << 4) + lane16][(ks << 5) + (quad << 3)];
      dacc = __builtin_amdgcn_mfma_f32_16x16x32_bf16(ea, ones, dacc, 0, 0, 0);
      s8v bc0 = *(const s8v*)&Kc[ 0 + lane16][(ks << 5) + (quad << 3)];
      s8v bc1 = *(const s8v*)&Kc[16 + lane16][(ks << 5) + (quad << 3)];
      s8v bc2 = *(const s8v*)&Kc[32 + lane16][(ks << 5) + (quad << 3)];
      s8v bc3 = *(const s8v*)&Kc[48 + lane16][(ks << 5) + (quad << 3)];
      o0 = __builtin_amdgcn_mfma_f32_16x16x32_bf16(ea, bc0, o0, 0, 0, 0);
      o1 = __builtin_amdgcn_mfma_f32_16x16x32_bf16(ea, bc1, o1, 0, 0, 0);
      o2 = __builtin_amdgcn_mfma_f32_16x16x32_bf16(ea, bc2, o2, 0, 0, 0);
      o3 = __builtin_amdgcn_mfma_f32_16x16x32_bf16(ea, bc3, o3, 0, 0, 0);
    }
  }
  {
    float inv0 = 1.f/dacc[0], inv1 = 1.f/dacc[1], inv2 = 1.f/dacc[2], inv3 = 1.f/dacc[3];
    const int pxl = (w << 4) + (quad << 2);
    XO[ 0 + lane16][pxl+0] = o0[0]*inv0; XO[ 0 + lane16][pxl+1] = o0[1]*inv1;
    XO[ 0 + lane16][pxl+2] = o0[2]*inv2; XO[ 0 + lane16][pxl+3] = o0[3]*inv3;
    XO[16 + lane16][pxl+0] = o1[0]*inv0; XO[16 + lane16][pxl+1] = o1[1]*inv1;
    XO[16 + lane16][pxl+2] = o1[2]*inv2; XO[16 + lane16][pxl+3] = o1[3]*inv3;
    XO[32 + lane16][pxl+0] = o2[0]*inv0; XO[32 + lane16][pxl+1] = o2[1]*inv1;
    XO[32 + lane16][pxl+2] = o2[2]*inv2; XO[32 + lane16][pxl+3] = o2[3]*inv3;
    XO[48 + lane16][pxl+0] = o3[0]*inv0; XO[48 + lane16][pxl+1] = o3[1]*inv1;
    XO[48 + lane16][pxl+2] = o3[2]*inv2; XO[48 + lane16][pxl+3] = o3[3]*inv3;
  }
  __syncthreads();
  {
    const int ch = t >> 2;
    float lsum = 0.f, lsq = 0.f;
    #pragma unroll
    for (int i = 0; i < 4; ++i){
      size_t gi = ((size_t)b << 16) + ((size_t)ch << 10) + p0 + g4 + (i << 2);
      float4 cv = *(const float4*)(c_t + gi);
      float4 ov;
      ov.x = cv.x + XO[ch][g4 + (i << 2) + 0];
      ov.y = cv.y + XO[ch][g4 + (i << 2) + 1];
      ov.z = cv.z + XO[ch][g4 + (i << 2) + 2];
      ov.w = cv.w + XO[ch][g4 + (i << 2) + 3];
      *(float4*)(sp_raw + gi) = ov;
      lsum += ov.x + ov.y + ov.z + ov.w;
      lsq  += ov.x*ov.x + ov.y*ov.y + ov.z*ov.z + ov.w*ov.w;
    }
    red_atomic2(lsum, lsq, stats, b, t);
  }
}

// ---------------------------------------------------------------------------
// Channel attention logits via MFMA: lg[b][c][l*64+c'] = sum_p ft[c][p] kv[l,c'][p]
// Block: M=64 x N=128 (one l-pair) x K=1024.
// ---------------------------------------------------------------------------
__global__ __launch_bounds__(256) void k_chlog_m(
    const ushort* __restrict__ ftC, const ushort* __restrict__ kvC, float* __restrict__ lg)
{
  const int lp = blockIdx.x, b = blockIdx.y;
  const int t = threadIdx.x, w = t >> 6, l = t & 63;
  const int lane16 = l & 15, quad = l >> 4;
  __shared__ __align__(16) ushort As[8][64][8];
  __shared__ __align__(16) ushort Bs[8][128][8];
  f4v acc[4][2];
  #pragma unroll
  for (int mi = 0; mi < 4; ++mi){ acc[mi][0] = (f4v){0.f,0.f,0.f,0.f}; acc[mi][1] = (f4v){0.f,0.f,0.f,0.f}; }

  for (int kc = 0; kc < 16; ++kc){
    __syncthreads();
    #pragma unroll
    for (int it = 0; it < 2; ++it){
      const int idx = t + it*256;
      const int c = idx >> 3, q = idx & 7;
      *(uint4*)&As[q][c][0] = *(const uint4*)(ftC + (((size_t)(b*64 + c)) << 10) + (kc<<6) + (q<<3));
    }
    #pragma unroll
    for (int it = 0; it < 4; ++it){
      const int idx = t + it*256;
      const int r2 = idx >> 3, q = idx & 7;
      const int plane = (b<<2) + (lp<<1) + (r2>>6);
      *(uint4*)&Bs[q][r2][0] = *(const uint4*)(kvC + ((((size_t)plane << 6) + (r2 & 63)) << 10) + (kc<<6) + (q<<3));
    }
    __syncthreads();
    #pragma unroll
    for (int ks = 0; ks < 2; ++ks){
      s8v a[4];
      #pragma unroll
      for (int mi = 0; mi < 4; ++mi)
        a[mi] = *(const s8v*)&As[(ks<<2)+quad][mi*16 + lane16][0];
      #pragma unroll
      for (int nt = 0; nt < 2; ++nt){
        s8v bb = *(const s8v*)&Bs[(ks<<2)+quad][(w<<5) + (nt<<4) + lane16][0];
        #pragma unroll
        for (int mi = 0; mi < 4; ++mi)
          acc[mi][nt] = __builtin_amdgcn_mfma_f32_16x16x32_bf16(a[mi], bb, acc[mi][nt], 0, 0, 0);
      }
    }
  }
  #pragma unroll
  for (int mi = 0; mi < 4; ++mi)
    #pragma unroll
    for (int nt = 0; nt < 2; ++nt)
      #pragma unroll
      for (int i = 0; i < 4; ++i){
        const int c = mi*16 + (quad<<2) + i;
        const int n = (lp<<7) + (w<<5) + (nt<<4) + lane16;
        lg[(((size_t)(b*64 + c)) << 8) + n] = acc[mi][nt][i];
      }
}

// softmax over 256 + bf16 pack
__global__ __launch_bounds__(256) void k_chsm(const float* __restrict__ a, ushort* __restrict__ ab)
{
  const int row  = blockIdx.x*4 + (threadIdx.x >> 6);
  const int lane = threadIdx.x & 63;
  const float* rp = a + ((size_t)row << 8);
  float v0 = rp[lane], v1 = rp[lane+64], v2 = rp[lane+128], v3 = rp[lane+192];
  float mx = fmaxf(fmaxf(v0, v1), fmaxf(v2, v3));
  #pragma unroll
  for (int m = 32; m; m >>= 1) mx = fmaxf(mx, __shfl_xor(mx, m));
  v0 = __expf(v0 - mx); v1 = __expf(v1 - mx); v2 = __expf(v2 - mx); v3 = __expf(v3 - mx);
  float s = v0 + v1 + v2 + v3;
  #pragma unroll
  for (int m = 32; m; m >>= 1) s += __shfl_xor(s, m);
  float inv = 1.f / s;
  ushort* op = ab + ((size_t)row << 8);
  op[lane] = f2b(v0*inv); op[lane+64] = f2b(v1*inv);
  op[lane+128] = f2b(v2*inv); op[lane+192] = f2b(v3*inv);
}

// ---------------------------------------------------------------------------
// Channel attention output via MFMA: out[c][p] = sum_k P[c][k] kvT[k][p], K=256
// Block: M=64 x N=128 px. A-frags hoisted to regs.
// ---------------------------------------------------------------------------
__global__ __launch_bounds__(256) void k_chout_m(
    const ushort* __restrict__ chlb, const ushort* __restrict__ kvT,
    const float* __restrict__ c_t, float* __restrict__ ch_raw, float* __restrict__ stats)
{
  const int p0 = blockIdx.x << 7, b = blockIdx.y;
  const int t = threadIdx.x, w = t >> 6, l = t & 63;
  const int lane16 = l & 15, quad = l >> 4;
  __shared__ __align__(16) ushort As[32][64][8];
  __shared__ __align__(16) ushort Bs[32][32][8];
  #pragma unroll
  for (int it = 0; it < 8; ++it){
    const int idx = t + it*256;
    const int c = idx >> 5, q = idx & 31;
    *(uint4*)&As[q][c][0] = *(const uint4*)(chlb + (((size_t)(b*64 + c)) << 8) + (q<<3));
  }
  __syncthreads();
  s8v a[8];
  #pragma unroll
  for (int ks = 0; ks < 8; ++ks)
    a[ks] = *(const s8v*)&As[(ks<<2)+quad][(w<<4) + lane16][0];
  float lsum = 0.f, lsq = 0.f;
  for (int pc = 0; pc < 4; ++pc){
    __syncthreads();
    #pragma unroll
    for (int it = 0; it < 4; ++it){
      const int idx = t + it*256;
      const int px = idx >> 5, q = idx & 31;
      const int plane = (b<<2) + (q>>3);
      *(uint4*)&Bs[q][px][0] = *(const uint4*)(kvT + ((((size_t)plane << 10) + p0 + (pc<<5) + px) << 6) + ((q&7)<<3));
    }
    __syncthreads();
    #pragma unroll
    for (int nt = 0; nt < 2; ++nt){
      f4v o = {0.f,0.f,0.f,0.f};
      #pragma unroll
      for (int ks = 0; ks < 8; ++ks){
        s8v bb = *(const s8v*)&Bs[(ks<<2)+quad][(nt<<4) + lane16][0];
        o = __builtin_amdgcn_mfma_f32_16x16x32_bf16(a[ks], bb, o, 0, 0, 0);
      }
      #pragma unroll
      for (int i = 0; i < 4; ++i){
        const int c = (w<<4) + (quad<<2) + i;
        const int px = p0 + (pc<<5) + (nt<<4) + lane16;
        size_t gi = ((size_t)b << 16) + ((size_t)c << 10) + px;
        float v = c_t[gi] + o[i];
        ch_raw[gi] = v;
        lsum += v; lsq += v*v;
      }
    }
  }
  red_atomic2(lsum, lsq, stats, b, t);
}

// ---------------------------------------------------------------------------
// LN+relu both attention branches, 1x1 convs, sum, 1x1 attn_w, c_new
// ---------------------------------------------------------------------------
__global__ __launch_bounds__(256) void k_attnfinal(
    const float* __restrict__ samid, const float* __restrict__ camid,
    const float* __restrict__ stats_sa, const float* __restrict__ stats_ca,
    const float* __restrict__ salng, const float* __restrict__ salnb,
    const float* __restrict__ calng, const float* __restrict__ calnb,
    const float* __restrict__ wsa2, const float* __restrict__ wca2,
    const float* __restrict__ cab2, const float* __restrict__ wat,
    const float* __restrict__ ig, float* __restrict__ out_c, float* __restrict__ memo)
{
  const int p0 = blockIdx.x << 6, b = blockIdx.y, t = threadIdx.x;
  const int tc = t & 15, tp = t >> 4;
  __shared__ __align__(16) float R[64][68];
  __shared__ __align__(16) float Wl[64][68];
  __shared__ __align__(16) float Ms[64][68];
  const float invN = 1.f/65536.f;
  float acc[4][4] = {};
  #pragma unroll
  for (int pass = 0; pass < 2; ++pass){
    const float* mid = pass ? camid : samid;
    const float* st  = pass ? stats_ca : stats_sa;
    const float* g   = pass ? calng : salng;
    const float* bb  = pass ? calnb : salnb;
    const float* w   = pass ? wca2  : wsa2;
    float mean = st[b*2]*invN;
    float var  = st[b*2+1]*invN - mean*mean;
    float rstd = rsqrtf(var + 1e-5f);
    __syncthreads();
    {
      const int j = t & 63, c0 = t >> 6;
      for (int ci = c0; ci < 64; ci += 4){
        size_t gi = ((size_t)b << 16) + ((size_t)ci << 10) + p0 + j;
        size_t li = ((size_t)ci << 10) + p0 + j;
        float v = (mid[gi] - mean)*rstd*g[li] + bb[li];
        R[ci][j] = fmaxf(v, 0.f);
      }
      const int ci2 = t & 63, c20 = t >> 6;
      for (int c2 = c20; c2 < 64; c2 += 4) Wl[ci2][c2] = w[((size_t)c2 << 6) + ci2];
    }
    __syncthreads();
    for (int ci = 0; ci < 64; ++ci){
      float wv[4], rv[4];
      *(float4*)wv = *(const float4*)&Wl[ci][4*tc];
      *(float4*)rv = *(const float4*)&R[ci][4*tp];
      #pragma unroll
      for (int i = 0; i < 4; ++i)
        #pragma unroll
        for (int j = 0; j < 4; ++j)
          acc[i][j] = fmaf(wv[i], rv[j], acc[i][j]);
    }
  }
  {
    float b2[4];
    #pragma unroll
    for (int i = 0; i < 4; ++i) b2[i] = cab2[4*tc + i];
    #pragma unroll
    for (int i = 0; i < 4; ++i)
      #pragma unroll
      for (int j = 0; j < 4; ++j)
        Ms[4*tc+i][4*tp+j] = acc[i][j] + b2[i];
  }
  __syncthreads();
  {
    const int ci2 = t & 63, c20 = t >> 6;
    for (int c2 = c20; c2 < 64; c2 += 4) Wl[ci2][c2] = wat[((size_t)c2 << 6) + ci2];
  }
  __syncthreads();
  float acc2[4][4] = {};
  for (int c2 = 0; c2 < 64; ++c2){
    float wv[4], mv[4];
    *(float4*)wv = *(const float4*)&Wl[c2][4*tc];
    *(float4*)mv = *(const float4*)&Ms[c2][4*tp];
    #pragma unroll
    for (int i = 0; i < 4; ++i)
      #pragma unroll
      for (int j = 0; j < 4; ++j)
        acc2[i][j] = fmaf(wv[i], mv[j], acc2[i][j]);
  }
  #pragma unroll
  for (int i = 0; i < 4; ++i)
    #pragma unroll
    for (int j = 0; j < 4; ++j){
      size_t gi = ((size_t)b << 16) + ((size_t)(4*tc + i) << 10) + p0 + 4*tp + j;
      float v = acc2[i][j] + ig[gi];
      out_c[gi] = v;
      memo[((size_t)(b*128 + 4*tc + i) << 10) + p0 + 4*tp + j] = v;
    }
}

// ---------------------------------------------------------------------------
__global__ __launch_bounds__(256) void k_final(
    const float* __restrict__ memo, const float* __restrict__ wlast,
    const float* __restrict__ bufo, const float* __restrict__ osum,
    const float* __restrict__ stats_o, const float* __restrict__ lnog, const float* __restrict__ lnob,
    float* __restrict__ out_h)
{
  const int p0 = blockIdx.x << 6, b = blockIdx.y, t = threadIdx.x;
  const int tc = t & 15, tp = t >> 4;
  __shared__ __align__(16) float Msh[64][68];
  __shared__ __align__(16) float Wt[64][68];
  float acc[4][4] = {};
  #pragma unroll
  for (int half = 0; half < 2; ++half){
    __syncthreads();
    {
      const int j = t & 63, c0 = t >> 6;
      for (int ci = c0; ci < 64; ci += 4)
        Msh[ci][j] = memo[((size_t)(b*128 + half*64 + ci) << 10) + p0 + j];
      const int ci2 = t & 63, co0 = t >> 6;
      for (int co = co0; co < 64; co += 4) Wt[ci2][co] = wlast[((size_t)co << 7) + half*64 + ci2];
    }
    __syncthreads();
    for (int ci = 0; ci < 64; ++ci){
      float wv[4], mv[4];
      *(float4*)wv = *(const float4*)&Wt[ci][4*tc];
      *(float4*)mv = *(const float4*)&Msh[ci][4*tp];
      #pragma unroll
      for (int i = 0; i < 4; ++i)
        #pragma unroll
        for (int j = 0; j < 4; ++j)
          acc[i][j] = fmaf(wv[i], mv[j], acc[i][j]);
    }
  }
  float mean = stats_o[b*2]*(1.f/65536.f);
  float var  = stats_o[b*2+1]*(1.f/65536.f) - mean*mean;
  float rstd = rsqrtf(var + 1e-5f);
  #pragma unroll
  for (int i = 0; i < 4; ++i)
    #pragma unroll
    for (int j = 0; j < 4; ++j){
      const int co = 4*tc + i, p = p0 + 4*tp + j;
      size_t gi = ((size_t)b << 16) + ((size_t)co << 10) + p;
      size_t li = ((size_t)co << 10) + p;
      float lno = (bufo[gi] - mean)*rstd*lnog[li] + lnob[li];
      float o = sigm(osum[gi] + lno);
      out_h[gi] = o * tanh_(acc[i][j]);
    }
}

// ---------------------------------------------------------------------------
extern "C" void kernel_launch(void* const* d_in, const int* in_sizes, int n_in,
                              void* d_out, int out_size, void* d_ws, size_t ws_size,
                              hipStream_t stream)
{
  const float* x_t   = (const float*)d_in[0];
  const float* h_t   = (const float*)d_in[1];
  const float* c_t   = (const float*)d_in[2];
  const float* chist = (const float*)d_in[3];
  const float* m_t   = (const float*)d_in[4];
  const float* w_x   = (const float*)d_in[5];
  const float* lnxg  = (const float*)d_in[6];
  const float* lnxb  = (const float*)d_in[7];
  const float* w_h   = (const float*)d_in[8];
  const float* lnhg  = (const float*)d_in[9];
  const float* lnhb  = (const float*)d_in[10];
  const float* w_m   = (const float*)d_in[11];
  const float* lnmg  = (const float*)d_in[12];
  const float* lnmb  = (const float*)d_in[13];
  const float* w_o   = (const float*)d_in[14];
  const float* lnog  = (const float*)d_in[15];
  const float* lnob  = (const float*)d_in[16];
  const float* w_last= (const float*)d_in[17];
  const float* sng   = (const float*)d_in[18];
  const float* snb   = (const float*)d_in[19];
  const float* cng   = (const float*)d_in[20];
  const float* cnb   = (const float*)d_in[21];
  const float* ca_w1 = (const float*)d_in[22];
  const float* ca_b1 = (const float*)d_in[23];
  const float* calng = (const float*)d_in[24];
  const float* calnb = (const float*)d_in[25];
  const float* ca_w2 = (const float*)d_in[26];
  const float* ca_b2 = (const float*)d_in[27];
  const float* sa_w1 = (const float*)d_in[28];
  const float* salng = (const float*)d_in[29];
  const float* salnb = (const float*)d_in[30];
  const float* sa_w2 = (const float*)d_in[31];
  const float* attn_w= (const float*)d_in[32];

  float* out = (float*)d_out;
  float* ws  = (float*)d_ws;

  float* stats = ws;                        // 8 groups x 16 batches x {sum,sumsq}
  float* bufx  = ws + 1024;                 // 7*N1 raw conv_x
  float* bufh  = bufx + 7*(size_t)N1;       // 4*N1
  float* bufm  = bufh + 4*(size_t)N1;       // 3*N1
  float* ft    = bufm + 3*(size_t)N1;       // N1
  float* ig    = ft   + (size_t)N1;         // N1
  float* osum  = ig   + (size_t)N1;         // N1
  float* memo  = osum + (size_t)N1;         // 2*N1
  // aliases valid AFTER k_gates consumed bufx/h/m:
  float* sp    = bufx;                      // N1
  float* ch    = bufx + (size_t)N1;         // N1
  float* samid = bufx + 2*(size_t)N1;       // N1
  float* camid = bufx + 3*(size_t)N1;       // N1
  float* bufo  = bufx + 4*(size_t)N1;       // N1
  float* chl   = bufx + 5*(size_t)N1;       // channel-attn logits fp32 (1 MB)
  ushort* kvC  = (ushort*)bufh;             // 4M bf16 (8 MB)
  ushort* kvT  = kvC + 4*(size_t)N1;        // 4M bf16 (8 MB)
  ushort* qT   = (ushort*)bufm;             // 1M bf16 (2 MB)
  ushort* ftC  = qT + (size_t)N1;           // 1M bf16 (2 MB)

  // bf16 weights: xhm pack lives in ft region (free until k_gates writes it)
  ushort* wbx = (ushort*)ft;                // 716800
  ushort* wbh = wbx + 716800;               // 409600
  ushort* wbm = wbh + 409600;               // 307200
  // o/sa/ca pack + bf16 probs live after chl in bufx region (free after k_gates)
  ushort* wbo  = (ushort*)(chl + 262144);   // 204800
  ushort* wbsa = wbo + 204800;              // 102400
  ushort* wbca = wbsa + 102400;             // 102400
  ushort* chlb = wbca + 102400;             // 262144 (bf16 probs)

  float* out_h = out;
  float* out_c = out + (size_t)N1;
  float* out_m = out + 2*(size_t)N1;

  k_zero<<<dim3(1), dim3(256), 0, stream>>>(stats);

  // bf16 weight prep for x/h/m convs
  k_wprep3<<<dim3(5600), dim3(256), 0, stream>>>(
      w_x, wbx, 448, 64, 716800,
      w_h, wbh, 256, 64, 409600,
      w_m, wbm, 192, 64, 307200);

  // big convs (MFMA, dy-group pipelined) + LN stats (stats: x=0, h=32, m=64)
  k_conv5g<4><<<dim3(56,16), dim3(256), 0, stream>>>(x_t, 64, wbx, nullptr, bufx, 448, stats+0,
                                                     nullptr, 0.f, nullptr, nullptr);
  k_conv5g<4><<<dim3(32,16), dim3(256), 0, stream>>>(h_t, 64, wbh, nullptr, bufh, 256, stats+32,
                                                     nullptr, 0.f, nullptr, nullptr);
  k_conv5g<4><<<dim3(24,16), dim3(256), 0, stream>>>(m_t, 64, wbm, nullptr, bufm, 192, stats+64,
                                                     nullptr, 0.f, nullptr, nullptr);

  k_gates<<<dim3(4096), dim3(256), 0, stream>>>(bufx, bufh, bufm, lnxg, lnxb, lnhg, lnhb,
                                                lnmg, lnmb, m_t, stats,
                                                ft, ig, osum, memo, out_m);

  // bf16 weight prep for o/sa/ca convs (regions free only after k_gates)
  k_wprep3<<<dim3(1600), dim3(256), 0, stream>>>(
      w_o,   wbo,  64, 128, 204800,
      sa_w1, wbsa, 64,  64, 102400,
      ca_w1, wbca, 64,  64, 102400);

  // bf16 prep for attention
  k_prep<<<dim3(16,64), dim3(256), 0, stream>>>(chist, kvC, kvT);
  k_prep<<<dim3(16,16), dim3(256), 0, stream>>>(ft, ftC, qT);

  // attention branches  (stats: sp=96, ch=128)
  k_spat_mfma<<<dim3(16,16), dim3(256), 0, stream>>>(qT, kvC, kvT, c_t, sp, stats+96);
  k_chlog_m<<<dim3(2,16), dim3(256), 0, stream>>>(ftC, kvC, chl);
  k_chsm  <<<dim3(256),  dim3(256), 0, stream>>>(chl, chlb);
  k_chout_m<<<dim3(8,16), dim3(256), 0, stream>>>(chlb, kvT, c_t, ch, stats+128);

  // 5x5 MFMA convs over LN(sp)/LN(ch)  (stats: sa=160, ca=192)
  k_conv5g<2><<<dim3(16,16), dim3(256), 0, stream>>>(sp, 64, wbsa, nullptr, samid, 64, stats+160,
                                                     stats+96, 1.f/65536.f, sng, snb);
  k_conv5g<2><<<dim3(16,16), dim3(256), 0, stream>>>(ch, 64, wbca, ca_b1, camid, 64, stats+192,
                                                     stats+128, 1.f/65536.f, cng, cnb);

  k_attnfinal<<<dim3(16,16), dim3(256), 0, stream>>>(samid, camid, stats+160, stats+192,
                                                     salng, salnb, calng, calnb,
                                                     sa_w2, ca_w2, ca_b2, attn_w,
                                                     ig, out_c, memo);

  // conv_o over mem (Cin=128)  (stats: o=224)
  k_conv5g<2><<<dim3(16,16), dim3(256), 0, stream>>>(memo, 128, wbo, nullptr, bufo, 64, stats+224,
                                                     nullptr, 0.f, nullptr, nullptr);

  k_final<<<dim3(16,16), dim3(256), 0, stream>>>(memo, w_last, bufo, osum, stats+224,
                                                 lnog, lnob, out_h);
}

// Round 5
// 526.046 us; speedup vs baseline: 5.3848x; 1.3034x over previous
//
#include <hip/hip_runtime.h>
#include <hip/hip_bf16.h>

#define N1 (1u << 20)   // B*NH*HW = 16*64*1024

typedef __attribute__((ext_vector_type(8))) short s8v;
typedef __attribute__((ext_vector_type(4))) float f4v;

static __device__ __forceinline__ float sigm(float x){ return 1.f/(1.f + __expf(-x)); }
static __device__ __forceinline__ float tanh_(float x){ return 1.f - 2.f/(__expf(2.f*x) + 1.f); }

static __device__ __forceinline__ ushort f2b(float f){
  union { float f; uint u; } x; x.f = f;
  uint r = x.u + 0x7FFFu + ((x.u >> 16) & 1u);
  return (ushort)(r >> 16);
}

static __device__ __forceinline__ void red_atomic2(float s, float q, float* d, int b, int t){
  #pragma unroll
  for (int m = 32; m; m >>= 1){ s += __shfl_xor(s, m); q += __shfl_xor(q, m); }
  if ((t & 63) == 0){ atomicAdd(&d[b*2], s); atomicAdd(&d[b*2+1], q); }
}

__global__ void k_zero(float* __restrict__ p){ p[threadIdx.x] = 0.f; }

// ---------------------------------------------------------------------------
// Weight prep: fp32 [Co][Ci][5][5] -> bf16 [tap][Co][Ci], three convs fused.
// ---------------------------------------------------------------------------
__global__ __launch_bounds__(256) void k_wprep3(
    const float* __restrict__ sA, ushort* __restrict__ dA, int CoA, int CiA, int nA,
    const float* __restrict__ sB, ushort* __restrict__ dB, int CoB, int CiB, int nB,
    const float* __restrict__ sC, ushort* __restrict__ dC, int CoC, int CiC, int nC)
{
  int idx = blockIdx.x*256 + threadIdx.x;
  const float* s; ushort* d; int Co, Ci;
  if (idx < nA){ s=sA; d=dA; Co=CoA; Ci=CiA; }
  else if ((idx -= nA) < nB){ s=sB; d=dB; Co=CoB; Ci=CiB; }
  else if ((idx -= nB) < nC){ s=sC; d=dC; Co=CoC; Ci=CiC; }
  else return;
  int ci = idx % Ci; int r = idx / Ci; int co = r % Co; int tap = r / Co;
  d[idx] = f2b(s[((size_t)(co*Ci + ci))*25 + tap]);
}

// ---------------------------------------------------------------------------
// Fused multi-segment MFMA 5x5 SAME conv.
// Block: MT*16 co x 8 rows (256 px). Wave w owns rows {2w,2w+1} (4 n-tiles).
// Weights per dy-row (5 taps) double-buffered in LDS, register-prefetched.
// Segment table in kernel args selects input/weights/output per cog range.
// ---------------------------------------------------------------------------
struct Seg {
  const float* in; const ushort* w; const float* bias;
  float* out; float* ostat; const float* istat;
  const float* g; const float* bb;
  int Cin, Cout; float invN;
};
struct Segs3 { Seg s[3]; int b1, b2; };

template<int MT>
__global__ __launch_bounds__(256, 2) void k_convX(Segs3 Sg)
{
  constexpr int CO  = MT*16;
  constexpr int NW  = 5*CO*4;
  constexpr int ITW = (NW + 255) / 256;

  const int b = blockIdx.y;
  const int cog = blockIdx.x >> 2, pxblk = blockIdx.x & 3;
  const int si = (cog >= Sg.b1) + (cog >= Sg.b2);
  const Seg sg = Sg.s[si];
  const int base = si == 0 ? 0 : (si == 1 ? Sg.b1 : Sg.b2);
  const int co0 = (cog - base) * CO;
  const int r0 = pxblk << 3;
  const int t = threadIdx.x, w = t >> 6, l = t & 63;
  const int lane16 = l & 15, quad = l >> 4;

  __shared__ __align__(16) ushort S_[4][12][36][8];       // [ci-quad][row][col][8ci]
  __shared__ __align__(16) ushort W_[2][4][5][CO][8];     // [buf][ci-quad][dx][co][8ci]

  f4v acc[MT][4];
  #pragma unroll
  for (int mi = 0; mi < MT; ++mi)
    #pragma unroll
    for (int n = 0; n < 4; ++n) acc[mi][n] = (f4v){0.f,0.f,0.f,0.f};

  float mean = 0.f, rstd = 0.f;
  if (sg.istat){
    float s0 = sg.istat[b*2], s1 = sg.istat[b*2+1];
    mean = s0 * sg.invN;
    rstd = rsqrtf(s1 * sg.invN - mean*mean + 1e-5f);
  }

  const int ncc = sg.Cin >> 5;
  for (int cc = 0; cc < ncc; ++cc){
    __syncthreads();
    // ---- stage input stripe: rows r0-2..r0+9, cols -2..33, 32 ci ----
    for (int idx = t; idx < 432; idx += 256){
      const int row = idx / 36, col = idx - row*36;
      const int ir = r0 - 2 + row, ic = col - 2;
      uint4 pk[4] = {make_uint4(0,0,0,0),make_uint4(0,0,0,0),make_uint4(0,0,0,0),make_uint4(0,0,0,0)};
      if ((unsigned)ir < 32u && (unsigned)ic < 32u){
        const int pix = (ir << 5) + ic;
        const float* bp = sg.in + (((size_t)(b*sg.Cin + (cc<<5))) << 10) + pix;
        #pragma unroll
        for (int q = 0; q < 4; ++q){
          uint hw[4];
          #pragma unroll
          for (int jj = 0; jj < 4; ++jj){
            const int c0 = q*8 + jj*2;
            float v0 = bp[(size_t)c0 << 10];
            float v1 = bp[(size_t)(c0+1) << 10];
            if (sg.g){
              const size_t li0 = (((size_t)((cc<<5)+c0)) << 10) + pix;
              v0 = (v0 - mean)*rstd*sg.g[li0] + sg.bb[li0];
              v1 = (v1 - mean)*rstd*sg.g[li0+1024] + sg.bb[li0+1024];
            }
            hw[jj] = (uint)f2b(v0) | ((uint)f2b(v1) << 16);
          }
          pk[q] = make_uint4(hw[0], hw[1], hw[2], hw[3]);
        }
      }
      #pragma unroll
      for (int q = 0; q < 4; ++q) *(uint4*)&S_[q][row][col][0] = pk[q];
    }
    // ---- stage weight group dy=0 ----
    #pragma unroll
    for (int it = 0; it < ITW; ++it){
      const int idx = t + it*256;
      if (ITW*256 == NW || idx < NW){
        const int q = idx & 3, r = idx >> 2;
        const int co = r & (CO - 1), dx = r / CO;
        uint4 wv = *(const uint4*)(sg.w + ((size_t)(dx*sg.Cout + co0+co))*sg.Cin + (cc<<5) + (q<<3));
        *(uint4*)&W_[0][q][dx][co][0] = wv;
      }
    }
    __syncthreads();
    for (int dy = 0; dy < 5; ++dy){
      uint4 wreg[ITW];
      if (dy < 4){
        #pragma unroll
        for (int it = 0; it < ITW; ++it){
          const int idx = t + it*256;
          if (ITW*256 == NW || idx < NW){
            const int q = idx & 3, r = idx >> 2;
            const int co = r & (CO - 1), dx = r / CO;
            wreg[it] = *(const uint4*)(sg.w + ((size_t)(((dy+1)*5+dx)*sg.Cout + co0+co))*sg.Cin + (cc<<5) + (q<<3));
          }
        }
      }
      #pragma unroll
      for (int dx = 0; dx < 5; ++dx){
        s8v a[MT];
        #pragma unroll
        for (int mi = 0; mi < MT; ++mi)
          a[mi] = *(const s8v*)&W_[dy & 1][quad][dx][mi*16 + lane16][0];
        #pragma unroll
        for (int n = 0; n < 4; ++n){
          const int srow = (w<<1) + (n>>1) + dy;
          const int col = ((n&1)<<4) + lane16 + dx;
          s8v bb = *(const s8v*)&S_[quad][srow][col][0];
          #pragma unroll
          for (int mi = 0; mi < MT; ++mi)
            acc[mi][n] = __builtin_amdgcn_mfma_f32_16x16x32_bf16(a[mi], bb, acc[mi][n], 0, 0, 0);
        }
      }
      if (dy < 4){
        #pragma unroll
        for (int it = 0; it < ITW; ++it){
          const int idx = t + it*256;
          if (ITW*256 == NW || idx < NW){
            const int q = idx & 3, r = idx >> 2;
            const int co = r & (CO - 1), dx = r / CO;
            *(uint4*)&W_[(dy+1) & 1][q][dx][co][0] = wreg[it];
          }
        }
      }
      __syncthreads();
    }
  }
  // ---- epilogue ----
  float lsum = 0.f, lsq = 0.f;
  #pragma unroll
  for (int mi = 0; mi < MT; ++mi){
    const int co = co0 + mi*16 + (quad<<2);
    #pragma unroll
    for (int n = 0; n < 4; ++n){
      const int row = r0 + (w<<1) + (n>>1);
      const int col = ((n&1)<<4) + lane16;
      #pragma unroll
      for (int i = 0; i < 4; ++i){
        float v = acc[mi][n][i] + (sg.bias ? sg.bias[co+i] : 0.f);
        sg.out[(((size_t)(b*sg.Cout + co + i)) << 10) + (row<<5) + col] = v;
        lsum += v; lsq += v*v;
      }
    }
  }
  if (sg.ostat) red_atomic2(lsum, lsq, sg.ostat, b, t);
}

// ---------------------------------------------------------------------------
// Prep: fp32 [plane][64][1024] -> bf16 transposed [plane][1024][64] (outT),
// optional straight-cast copy (outC).
// ---------------------------------------------------------------------------
__global__ __launch_bounds__(256) void k_prep(const float* __restrict__ src,
                                              ushort* __restrict__ outC,
                                              ushort* __restrict__ outT)
{
  const int plane = blockIdx.y;
  const int p0 = blockIdx.x << 6;
  const float* sp = src + ((size_t)plane << 16);
  __shared__ __align__(16) float T[64][68];
  const int t = threadIdx.x, c = t >> 2, g = t & 3;
  #pragma unroll
  for (int i = 0; i < 4; ++i){
    float4 f = *(const float4*)(sp + ((size_t)c << 10) + p0 + (g << 4) + (i << 2));
    *(float4*)&T[c][(g << 4) + (i << 2)] = f;
    if (outC){
      uint2 pk2;
      pk2.x = (uint)f2b(f.x) | ((uint)f2b(f.y) << 16);
      pk2.y = (uint)f2b(f.z) | ((uint)f2b(f.w) << 16);
      *(uint2*)(outC + ((((size_t)plane << 6) + c) << 10) + p0 + (g << 4) + (i << 2)) = pk2;
    }
  }
  __syncthreads();
  const int p = t >> 2, c0 = (t & 3) << 4;
  uint w4[8];
  #pragma unroll
  for (int k = 0; k < 8; ++k){
    ushort lo = f2b(T[c0 + 2*k][p]);
    ushort hi = f2b(T[c0 + 2*k + 1][p]);
    w4[k] = (uint)lo | ((uint)hi << 16);
  }
  ushort* dst = outT + ((((size_t)plane << 10) + p0 + p) << 6) + c0;
  *(uint4*)(dst)     = *(uint4*)&w4[0];
  *(uint4*)(dst + 8) = *(uint4*)&w4[4];
}

// ---------------------------------------------------------------------------
// Gates
// ---------------------------------------------------------------------------
__global__ __launch_bounds__(256) void k_gates(
    const float* __restrict__ bufx, const float* __restrict__ bufh, const float* __restrict__ bufm,
    const float* __restrict__ lnxg, const float* __restrict__ lnxb,
    const float* __restrict__ lnhg, const float* __restrict__ lnhb,
    const float* __restrict__ lnmg, const float* __restrict__ lnmb,
    const float* __restrict__ m_t, const float* __restrict__ stats,
    float* __restrict__ ft, float* __restrict__ ig, float* __restrict__ osum,
    float* __restrict__ memo, float* __restrict__ out_m)
{
  const int idx = blockIdx.x*256 + threadIdx.x;
  const int b = idx >> 16, rem = idx & 65535;
  const int c = rem >> 10, p = rem & 1023;

  float mx = stats[b*2]      * (1.f/458752.f);
  float vx = stats[b*2+1]    * (1.f/458752.f) - mx*mx;  float rx = rsqrtf(vx + 1e-5f);
  float mh = stats[32+b*2]   * (1.f/262144.f);
  float vh = stats[32+b*2+1] * (1.f/262144.f) - mh*mh;  float rh = rsqrtf(vh + 1e-5f);
  float mm = stats[64+b*2]   * (1.f/196608.f);
  float vm = stats[64+b*2+1] * (1.f/196608.f) - mm*mm;  float rm = rsqrtf(vm + 1e-5f);

  auto LX = [&](int k){
    size_t ch = (size_t)k*64 + c; size_t gi = ((size_t)b*448 + ch)*1024 + p; size_t li = ch*1024 + p;
    return (bufx[gi] - mx)*rx*lnxg[li] + lnxb[li]; };
  auto LH = [&](int k){
    size_t ch = (size_t)k*64 + c; size_t gi = ((size_t)b*256 + ch)*1024 + p; size_t li = ch*1024 + p;
    return (bufh[gi] - mh)*rh*lnhg[li] + lnhb[li]; };
  auto LM = [&](int k){
    size_t ch = (size_t)k*64 + c; size_t gi = ((size_t)b*192 + ch)*1024 + p; size_t li = ch*1024 + p;
    return (bufm[gi] - mm)*rm*lnmg[li] + lnmb[li]; };

  float i_t = sigm(LX(0) + LH(0));
  float f_t = sigm(LX(1) + LH(1) + 1.f);
  float g_t = tanh_(LX(2) + LH(2));
  float i_p = sigm(LX(3) + LM(0));
  float f_p = sigm(LX(4) + LM(1) + 1.f);
  float g_p = tanh_(LX(5) + LM(2));
  float ox = LX(6), oh = LH(3);

  ft[idx]   = f_t;
  ig[idx]   = i_t * g_t;
  osum[idx] = ox + oh;
  float mn = f_p * m_t[idx] + i_p * g_p;
  out_m[idx] = mn;
  memo[((size_t)(b*128 + 64 + c) << 10) + p] = mn;
}

// ---------------------------------------------------------------------------
// Spatial attention via bf16 MFMA (fixed-shift softmax, additive num/den).
// ---------------------------------------------------------------------------
__global__ __launch_bounds__(256) void k_spat_mfma(
    const ushort* __restrict__ qT, const ushort* __restrict__ kvC, const ushort* __restrict__ kvT,
    const float* __restrict__ c_t, float* __restrict__ sp_raw, float* __restrict__ stats)
{
  const int p0 = blockIdx.x << 6, b = blockIdx.y;
  const int t = threadIdx.x, w = t >> 6, l = t & 63;
  const int lane16 = l & 15, quad = l >> 4;
  __shared__ __align__(16) ushort Kt[64][72];
  __shared__ __align__(16) ushort Kc[64][72];
  __shared__ __align__(16) ushort Eb[64][72];
  __shared__ __align__(16) float  XO[64][65];

  s8v qa0, qa1;
  {
    const ushort* qr = qT + ((((size_t)b << 10) + p0 + (w << 4) + lane16) << 6) + (quad << 3);
    qa0 = *(const s8v*)(qr);
    qa1 = *(const s8v*)(qr + 32);
  }
  f4v o0 = {0.f,0.f,0.f,0.f}, o1 = o0, o2 = o0, o3 = o0, dacc = o0;
  const short oneb = (short)0x3F80;
  const s8v ones = { oneb, oneb, oneb, oneb, oneb, oneb, oneb, oneb };

  const int r = t >> 2, g4 = (t & 3) << 4;
  for (int chunk = 0; chunk < 64; ++chunk){
    const int lidx = chunk >> 4, pk = (chunk & 15) << 6;
    __syncthreads();
    {
      const ushort* sc = kvC + ((((size_t)(b*4 + lidx) << 6) + r) << 10) + pk + g4;
      *(uint4*)&Kc[r][g4]     = *(const uint4*)(sc);
      *(uint4*)&Kc[r][g4 + 8] = *(const uint4*)(sc + 8);
      const ushort* st = kvT + ((((size_t)(b*4 + lidx) << 10) + pk + r) << 6) + g4;
      *(uint4*)&Kt[r][g4]     = *(const uint4*)(st);
      *(uint4*)&Kt[r][g4 + 8] = *(const uint4*)(st + 8);
    }
    __syncthreads();
    #pragma unroll
    for (int nt = 0; nt < 4; ++nt){
      const ushort* bt = &Kt[(nt << 4) + lane16][quad << 3];
      s8v b0 = *(const s8v*)(bt);
      s8v b1 = *(const s8v*)(bt + 32);
      f4v s = {0.f,0.f,0.f,0.f};
      s = __builtin_amdgcn_mfma_f32_16x16x32_bf16(qa0, b0, s, 0, 0, 0);
      s = __builtin_amdgcn_mfma_f32_16x16x32_bf16(qa1, b1, s, 0, 0, 0);
      #pragma unroll
      for (int i = 0; i < 4; ++i){
        float e = __expf(s[i] - 12.f);
        Eb[(w << 4) + (quad << 2) + i][(nt << 4) + lane16] = f2b(e);
      }
    }
    __syncthreads();
    #pragma unroll
    for (int ks = 0; ks < 2; ++ks){
      s8v ea = *(const s8v*)&Eb[(w << 4) + lane16][(ks << 5) + (quad << 3)];
      dacc = __builtin_amdgcn_mfma_f32_16x16x32_bf16(ea, ones, dacc, 0, 0, 0);
      s8v bc0 = *(const s8v*)&Kc[ 0 + lane16][(ks << 5) + (quad << 3)];
      s8v bc1 = *(const s8v*)&Kc[16 + lane16][(ks << 5) + (quad << 3)];
      s8v bc2 = *(const s8v*)&Kc[32 + lane16][(ks << 5) + (quad << 3)];
      s8v bc3 = *(const s8v*)&Kc[48 + lane16][(ks << 5) + (quad << 3)];
      o0 = __builtin_amdgcn_mfma_f32_16x16x32_bf16(ea, bc0, o0, 0, 0, 0);
      o1 = __builtin_amdgcn_mfma_f32_16x16x32_bf16(ea, bc1, o1, 0, 0, 0);
      o2 = __builtin_amdgcn_mfma_f32_16x16x32_bf16(ea, bc2, o2, 0, 0, 0);
      o3 = __builtin_amdgcn_mfma_f32_16x16x32_bf16(ea, bc3, o3, 0, 0, 0);
    }
  }
  {
    float inv0 = 1.f/dacc[0], inv1 = 1.f/dacc[1], inv2 = 1.f/dacc[2], inv3 = 1.f/dacc[3];
    const int pxl = (w << 4) + (quad << 2);
    XO[ 0 + lane16][pxl+0] = o0[0]*inv0; XO[ 0 + lane16][pxl+1] = o0[1]*inv1;
    XO[ 0 + lane16][pxl+2] = o0[2]*inv2; XO[ 0 + lane16][pxl+3] = o0[3]*inv3;
    XO[16 + lane16][pxl+0] = o1[0]*inv0; XO[16 + lane16][pxl+1] = o1[1]*inv1;
    XO[16 + lane16][pxl+2] = o1[2]*inv2; XO[16 + lane16][pxl+3] = o1[3]*inv3;
    XO[32 + lane16][pxl+0] = o2[0]*inv0; XO[32 + lane16][pxl+1] = o2[1]*inv1;
    XO[32 + lane16][pxl+2] = o2[2]*inv2; XO[32 + lane16][pxl+3] = o2[3]*inv3;
    XO[48 + lane16][pxl+0] = o3[0]*inv0; XO[48 + lane16][pxl+1] = o3[1]*inv1;
    XO[48 + lane16][pxl+2] = o3[2]*inv2; XO[48 + lane16][pxl+3] = o3[3]*inv3;
  }
  __syncthreads();
  {
    const int ch = t >> 2;
    float lsum = 0.f, lsq = 0.f;
    #pragma unroll
    for (int i = 0; i < 4; ++i){
      size_t gi = ((size_t)b << 16) + ((size_t)ch << 10) + p0 + g4 + (i << 2);
      float4 cv = *(const float4*)(c_t + gi);
      float4 ov;
      ov.x = cv.x + XO[ch][g4 + (i << 2) + 0];
      ov.y = cv.y + XO[ch][g4 + (i << 2) + 1];
      ov.z = cv.z + XO[ch][g4 + (i << 2) + 2];
      ov.w = cv.w + XO[ch][g4 + (i << 2) + 3];
      *(float4*)(sp_raw + gi) = ov;
      lsum += ov.x + ov.y + ov.z + ov.w;
      lsq  += ov.x*ov.x + ov.y*ov.y + ov.z*ov.z + ov.w*ov.w;
    }
    red_atomic2(lsum, lsq, stats, b, t);
  }
}

// ---------------------------------------------------------------------------
// Channel attention logits via MFMA
// ---------------------------------------------------------------------------
__global__ __launch_bounds__(256) void k_chlog_m(
    const ushort* __restrict__ ftC, const ushort* __restrict__ kvC, float* __restrict__ lg)
{
  const int lp = blockIdx.x, b = blockIdx.y;
  const int t = threadIdx.x, w = t >> 6, l = t & 63;
  const int lane16 = l & 15, quad = l >> 4;
  __shared__ __align__(16) ushort As[8][64][8];
  __shared__ __align__(16) ushort Bs[8][128][8];
  f4v acc[4][2];
  #pragma unroll
  for (int mi = 0; mi < 4; ++mi){ acc[mi][0] = (f4v){0.f,0.f,0.f,0.f}; acc[mi][1] = (f4v){0.f,0.f,0.f,0.f}; }

  for (int kc = 0; kc < 16; ++kc){
    __syncthreads();
    #pragma unroll
    for (int it = 0; it < 2; ++it){
      const int idx = t + it*256;
      const int c = idx >> 3, q = idx & 7;
      *(uint4*)&As[q][c][0] = *(const uint4*)(ftC + (((size_t)(b*64 + c)) << 10) + (kc<<6) + (q<<3));
    }
    #pragma unroll
    for (int it = 0; it < 4; ++it){
      const int idx = t + it*256;
      const int r2 = idx >> 3, q = idx & 7;
      const int plane = (b<<2) + (lp<<1) + (r2>>6);
      *(uint4*)&Bs[q][r2][0] = *(const uint4*)(kvC + ((((size_t)plane << 6) + (r2 & 63)) << 10) + (kc<<6) + (q<<3));
    }
    __syncthreads();
    #pragma unroll
    for (int ks = 0; ks < 2; ++ks){
      s8v a[4];
      #pragma unroll
      for (int mi = 0; mi < 4; ++mi)
        a[mi] = *(const s8v*)&As[(ks<<2)+quad][mi*16 + lane16][0];
      #pragma unroll
      for (int nt = 0; nt < 2; ++nt){
        s8v bb = *(const s8v*)&Bs[(ks<<2)+quad][(w<<5) + (nt<<4) + lane16][0];
        #pragma unroll
        for (int mi = 0; mi < 4; ++mi)
          acc[mi][nt] = __builtin_amdgcn_mfma_f32_16x16x32_bf16(a[mi], bb, acc[mi][nt], 0, 0, 0);
      }
    }
  }
  #pragma unroll
  for (int mi = 0; mi < 4; ++mi)
    #pragma unroll
    for (int nt = 0; nt < 2; ++nt)
      #pragma unroll
      for (int i = 0; i < 4; ++i){
        const int c = mi*16 + (quad<<2) + i;
        const int n = (lp<<7) + (w<<5) + (nt<<4) + lane16;
        lg[(((size_t)(b*64 + c)) << 8) + n] = acc[mi][nt][i];
      }
}

// softmax over 256 + bf16 pack
__global__ __launch_bounds__(256) void k_chsm(const float* __restrict__ a, ushort* __restrict__ ab)
{
  const int row  = blockIdx.x*4 + (threadIdx.x >> 6);
  const int lane = threadIdx.x & 63;
  const float* rp = a + ((size_t)row << 8);
  float v0 = rp[lane], v1 = rp[lane+64], v2 = rp[lane+128], v3 = rp[lane+192];
  float mx = fmaxf(fmaxf(v0, v1), fmaxf(v2, v3));
  #pragma unroll
  for (int m = 32; m; m >>= 1) mx = fmaxf(mx, __shfl_xor(mx, m));
  v0 = __expf(v0 - mx); v1 = __expf(v1 - mx); v2 = __expf(v2 - mx); v3 = __expf(v3 - mx);
  float s = v0 + v1 + v2 + v3;
  #pragma unroll
  for (int m = 32; m; m >>= 1) s += __shfl_xor(s, m);
  float inv = 1.f / s;
  ushort* op = ab + ((size_t)row << 8);
  op[lane] = f2b(v0*inv); op[lane+64] = f2b(v1*inv);
  op[lane+128] = f2b(v2*inv); op[lane+192] = f2b(v3*inv);
}

// ---------------------------------------------------------------------------
// Channel attention output via MFMA
// ---------------------------------------------------------------------------
__global__ __launch_bounds__(256) void k_chout_m(
    const ushort* __restrict__ chlb, const ushort* __restrict__ kvT,
    const float* __restrict__ c_t, float* __restrict__ ch_raw, float* __restrict__ stats)
{
  const int p0 = blockIdx.x << 7, b = blockIdx.y;
  const int t = threadIdx.x, w = t >> 6, l = t & 63;
  const int lane16 = l & 15, quad = l >> 4;
  __shared__ __align__(16) ushort As[32][64][8];
  __shared__ __align__(16) ushort Bs[32][32][8];
  #pragma unroll
  for (int it = 0; it < 8; ++it){
    const int idx = t + it*256;
    const int c = idx >> 5, q = idx & 31;
    *(uint4*)&As[q][c][0] = *(const uint4*)(chlb + (((size_t)(b*64 + c)) << 8) + (q<<3));
  }
  __syncthreads();
  s8v a[8];
  #pragma unroll
  for (int ks = 0; ks < 8; ++ks)
    a[ks] = *(const s8v*)&As[(ks<<2)+quad][(w<<4) + lane16][0];
  float lsum = 0.f, lsq = 0.f;
  for (int pc = 0; pc < 4; ++pc){
    __syncthreads();
    #pragma unroll
    for (int it = 0; it < 4; ++it){
      const int idx = t + it*256;
      const int px = idx >> 5, q = idx & 31;
      const int plane = (b<<2) + (q>>3);
      *(uint4*)&Bs[q][px][0] = *(const uint4*)(kvT + ((((size_t)plane << 10) + p0 + (pc<<5) + px) << 6) + ((q&7)<<3));
    }
    __syncthreads();
    #pragma unroll
    for (int nt = 0; nt < 2; ++nt){
      f4v o = {0.f,0.f,0.f,0.f};
      #pragma unroll
      for (int ks = 0; ks < 8; ++ks){
        s8v bb = *(const s8v*)&Bs[(ks<<2)+quad][(nt<<4) + lane16][0];
        o = __builtin_amdgcn_mfma_f32_16x16x32_bf16(a[ks], bb, o, 0, 0, 0);
      }
      #pragma unroll
      for (int i = 0; i < 4; ++i){
        const int c = (w<<4) + (quad<<2) + i;
        const int px = p0 + (pc<<5) + (nt<<4) + lane16;
        size_t gi = ((size_t)b << 16) + ((size_t)c << 10) + px;
        float v = c_t[gi] + o[i];
        ch_raw[gi] = v;
        lsum += v; lsq += v*v;
      }
    }
  }
  red_atomic2(lsum, lsq, stats, b, t);
}

// ---------------------------------------------------------------------------
// LN+relu both attention branches, 1x1 convs, sum, 1x1 attn_w, c_new
// ---------------------------------------------------------------------------
__global__ __launch_bounds__(256) void k_attnfinal(
    const float* __restrict__ samid, const float* __restrict__ camid,
    const float* __restrict__ stats_sa, const float* __restrict__ stats_ca,
    const float* __restrict__ salng, const float* __restrict__ salnb,
    const float* __restrict__ calng, const float* __restrict__ calnb,
    const float* __restrict__ wsa2, const float* __restrict__ wca2,
    const float* __restrict__ cab2, const float* __restrict__ wat,
    const float* __restrict__ ig, float* __restrict__ out_c, float* __restrict__ memo)
{
  const int p0 = blockIdx.x << 6, b = blockIdx.y, t = threadIdx.x;
  const int tc = t & 15, tp = t >> 4;
  __shared__ __align__(16) float R[64][68];
  __shared__ __align__(16) float Wl[64][68];
  __shared__ __align__(16) float Ms[64][68];
  const float invN = 1.f/65536.f;
  float acc[4][4] = {};
  #pragma unroll
  for (int pass = 0; pass < 2; ++pass){
    const float* mid = pass ? camid : samid;
    const float* st  = pass ? stats_ca : stats_sa;
    const float* g   = pass ? calng : salng;
    const float* bb  = pass ? calnb : salnb;
    const float* w   = pass ? wca2  : wsa2;
    float mean = st[b*2]*invN;
    float var  = st[b*2+1]*invN - mean*mean;
    float rstd = rsqrtf(var + 1e-5f);
    __syncthreads();
    {
      const int j = t & 63, c0 = t >> 6;
      for (int ci = c0; ci < 64; ci += 4){
        size_t gi = ((size_t)b << 16) + ((size_t)ci << 10) + p0 + j;
        size_t li = ((size_t)ci << 10) + p0 + j;
        float v = (mid[gi] - mean)*rstd*g[li] + bb[li];
        R[ci][j] = fmaxf(v, 0.f);
      }
      const int ci2 = t & 63, c20 = t >> 6;
      for (int c2 = c20; c2 < 64; c2 += 4) Wl[ci2][c2] = w[((size_t)c2 << 6) + ci2];
    }
    __syncthreads();
    for (int ci = 0; ci < 64; ++ci){
      float wv[4], rv[4];
      *(float4*)wv = *(const float4*)&Wl[ci][4*tc];
      *(float4*)rv = *(const float4*)&R[ci][4*tp];
      #pragma unroll
      for (int i = 0; i < 4; ++i)
        #pragma unroll
        for (int j = 0; j < 4; ++j)
          acc[i][j] = fmaf(wv[i], rv[j], acc[i][j]);
    }
  }
  {
    float b2[4];
    #pragma unroll
    for (int i = 0; i < 4; ++i) b2[i] = cab2[4*tc + i];
    #pragma unroll
    for (int i = 0; i < 4; ++i)
      #pragma unroll
      for (int j = 0; j < 4; ++j)
        Ms[4*tc+i][4*tp+j] = acc[i][j] + b2[i];
  }
  __syncthreads();
  {
    const int ci2 = t & 63, c20 = t >> 6;
    for (int c2 = c20; c2 < 64; c2 += 4) Wl[ci2][c2] = wat[((size_t)c2 << 6) + ci2];
  }
  __syncthreads();
  float acc2[4][4] = {};
  for (int c2 = 0; c2 < 64; ++c2){
    float wv[4], mv[4];
    *(float4*)wv = *(const float4*)&Wl[c2][4*tc];
    *(float4*)mv = *(const float4*)&Ms[c2][4*tp];
    #pragma unroll
    for (int i = 0; i < 4; ++i)
      #pragma unroll
      for (int j = 0; j < 4; ++j)
        acc2[i][j] = fmaf(wv[i], mv[j], acc2[i][j]);
  }
  #pragma unroll
  for (int i = 0; i < 4; ++i)
    #pragma unroll
    for (int j = 0; j < 4; ++j){
      size_t gi = ((size_t)b << 16) + ((size_t)(4*tc + i) << 10) + p0 + 4*tp + j;
      float v = acc2[i][j] + ig[gi];
      out_c[gi] = v;
      memo[((size_t)(b*128 + 4*tc + i) << 10) + p0 + 4*tp + j] = v;
    }
}

// ---------------------------------------------------------------------------
__global__ __launch_bounds__(256) void k_final(
    const float* __restrict__ memo, const float* __restrict__ wlast,
    const float* __restrict__ bufo, const float* __restrict__ osum,
    const float* __restrict__ stats_o, const float* __restrict__ lnog, const float* __restrict__ lnob,
    float* __restrict__ out_h)
{
  const int p0 = blockIdx.x << 6, b = blockIdx.y, t = threadIdx.x;
  const int tc = t & 15, tp = t >> 4;
  __shared__ __align__(16) float Msh[64][68];
  __shared__ __align__(16) float Wt[64][68];
  float acc[4][4] = {};
  #pragma unroll
  for (int half = 0; half < 2; ++half){
    __syncthreads();
    {
      const int j = t & 63, c0 = t >> 6;
      for (int ci = c0; ci < 64; ci += 4)
        Msh[ci][j] = memo[((size_t)(b*128 + half*64 + ci) << 10) + p0 + j];
      const int ci2 = t & 63, co0 = t >> 6;
      for (int co = co0; co < 64; co += 4) Wt[ci2][co] = wlast[((size_t)co << 7) + half*64 + ci2];
    }
    __syncthreads();
    for (int ci = 0; ci < 64; ++ci){
      float wv[4], mv[4];
      *(float4*)wv = *(const float4*)&Wt[ci][4*tc];
      *(float4*)mv = *(const float4*)&Msh[ci][4*tp];
      #pragma unroll
      for (int i = 0; i < 4; ++i)
        #pragma unroll
        for (int j = 0; j < 4; ++j)
          acc[i][j] = fmaf(wv[i], mv[j], acc[i][j]);
    }
  }
  float mean = stats_o[b*2]*(1.f/65536.f);
  float var  = stats_o[b*2+1]*(1.f/65536.f) - mean*mean;
  float rstd = rsqrtf(var + 1e-5f);
  #pragma unroll
  for (int i = 0; i < 4; ++i)
    #pragma unroll
    for (int j = 0; j < 4; ++j){
      const int co = 4*tc + i, p = p0 + 4*tp + j;
      size_t gi = ((size_t)b << 16) + ((size_t)co << 10) + p;
      size_t li = ((size_t)co << 10) + p;
      float lno = (bufo[gi] - mean)*rstd*lnog[li] + lnob[li];
      float o = sigm(osum[gi] + lno);
      out_h[gi] = o * tanh_(acc[i][j]);
    }
}

// ---------------------------------------------------------------------------
extern "C" void kernel_launch(void* const* d_in, const int* in_sizes, int n_in,
                              void* d_out, int out_size, void* d_ws, size_t ws_size,
                              hipStream_t stream)
{
  const float* x_t   = (const float*)d_in[0];
  const float* h_t   = (const float*)d_in[1];
  const float* c_t   = (const float*)d_in[2];
  const float* chist = (const float*)d_in[3];
  const float* m_t   = (const float*)d_in[4];
  const float* w_x   = (const float*)d_in[5];
  const float* lnxg  = (const float*)d_in[6];
  const float* lnxb  = (const float*)d_in[7];
  const float* w_h   = (const float*)d_in[8];
  const float* lnhg  = (const float*)d_in[9];
  const float* lnhb  = (const float*)d_in[10];
  const float* w_m   = (const float*)d_in[11];
  const float* lnmg  = (const float*)d_in[12];
  const float* lnmb  = (const float*)d_in[13];
  const float* w_o   = (const float*)d_in[14];
  const float* lnog  = (const float*)d_in[15];
  const float* lnob  = (const float*)d_in[16];
  const float* w_last= (const float*)d_in[17];
  const float* sng   = (const float*)d_in[18];
  const float* snb   = (const float*)d_in[19];
  const float* cng   = (const float*)d_in[20];
  const float* cnb   = (const float*)d_in[21];
  const float* ca_w1 = (const float*)d_in[22];
  const float* ca_b1 = (const float*)d_in[23];
  const float* calng = (const float*)d_in[24];
  const float* calnb = (const float*)d_in[25];
  const float* ca_w2 = (const float*)d_in[26];
  const float* ca_b2 = (const float*)d_in[27];
  const float* sa_w1 = (const float*)d_in[28];
  const float* salng = (const float*)d_in[29];
  const float* salnb = (const float*)d_in[30];
  const float* sa_w2 = (const float*)d_in[31];
  const float* attn_w= (const float*)d_in[32];

  float* out = (float*)d_out;
  float* ws  = (float*)d_ws;

  float* stats = ws;                        // 8 groups x 16 batches x {sum,sumsq}
  float* bufx  = ws + 1024;                 // 7*N1 raw conv_x
  float* bufh  = bufx + 7*(size_t)N1;       // 4*N1
  float* bufm  = bufh + 4*(size_t)N1;       // 3*N1
  float* ft    = bufm + 3*(size_t)N1;       // N1
  float* ig    = ft   + (size_t)N1;         // N1
  float* osum  = ig   + (size_t)N1;         // N1
  float* memo  = osum + (size_t)N1;         // 2*N1
  // aliases valid AFTER k_gates consumed bufx/h/m:
  float* sp    = bufx;                      // N1
  float* ch    = bufx + (size_t)N1;         // N1
  float* samid = bufx + 2*(size_t)N1;       // N1
  float* camid = bufx + 3*(size_t)N1;       // N1
  float* bufo  = bufx + 4*(size_t)N1;       // N1
  float* chl   = bufx + 5*(size_t)N1;       // channel-attn logits fp32 (1 MB)
  ushort* kvC  = (ushort*)bufh;             // 4M bf16 (8 MB)
  ushort* kvT  = kvC + 4*(size_t)N1;        // 4M bf16 (8 MB)
  ushort* qT   = (ushort*)bufm;             // 1M bf16 (2 MB)
  ushort* ftC  = qT + (size_t)N1;           // 1M bf16 (2 MB)

  // bf16 weights: xhm pack lives in ft region (free until k_gates writes it)
  ushort* wbx = (ushort*)ft;                // 716800
  ushort* wbh = wbx + 716800;               // 409600
  ushort* wbm = wbh + 409600;               // 307200
  // o/sa/ca pack + bf16 probs live after chl in bufx region (free after k_gates)
  ushort* wbo  = (ushort*)(chl + 262144);   // 204800
  ushort* wbsa = wbo + 204800;              // 102400
  ushort* wbca = wbsa + 102400;             // 102400
  ushort* chlb = wbca + 102400;             // 262144 (bf16 probs)

  float* out_h = out;
  float* out_c = out + (size_t)N1;
  float* out_m = out + 2*(size_t)N1;

  k_zero<<<dim3(1), dim3(256), 0, stream>>>(stats);

  // bf16 weight prep for x/h/m convs
  k_wprep3<<<dim3(5600), dim3(256), 0, stream>>>(
      w_x, wbx, 448, 64, 716800,
      w_h, wbh, 256, 64, 409600,
      w_m, wbm, 192, 64, 307200);

  // fused x+h+m MFMA conv, one dispatch (stats: x=0, h=32, m=64)
  {
    Segs3 XHM;
    XHM.s[0] = Seg{ x_t, wbx, nullptr, bufx, stats+0,  nullptr, nullptr, nullptr, 64, 448, 0.f };
    XHM.s[1] = Seg{ h_t, wbh, nullptr, bufh, stats+32, nullptr, nullptr, nullptr, 64, 256, 0.f };
    XHM.s[2] = Seg{ m_t, wbm, nullptr, bufm, stats+64, nullptr, nullptr, nullptr, 64, 192, 0.f };
    XHM.b1 = 7; XHM.b2 = 11;   // cogs: x 0-6, h 7-10, m 11-13
    k_convX<4><<<dim3(56,16), dim3(256), 0, stream>>>(XHM);
  }

  k_gates<<<dim3(4096), dim3(256), 0, stream>>>(bufx, bufh, bufm, lnxg, lnxb, lnhg, lnhb,
                                                lnmg, lnmb, m_t, stats,
                                                ft, ig, osum, memo, out_m);

  // bf16 weight prep for o/sa/ca convs (regions free only after k_gates)
  k_wprep3<<<dim3(1600), dim3(256), 0, stream>>>(
      w_o,   wbo,  64, 128, 204800,
      sa_w1, wbsa, 64,  64, 102400,
      ca_w1, wbca, 64,  64, 102400);

  // bf16 prep for attention
  k_prep<<<dim3(16,64), dim3(256), 0, stream>>>(chist, kvC, kvT);
  k_prep<<<dim3(16,16), dim3(256), 0, stream>>>(ft, ftC, qT);

  // attention branches  (stats: sp=96, ch=128)
  k_spat_mfma<<<dim3(16,16), dim3(256), 0, stream>>>(qT, kvC, kvT, c_t, sp, stats+96);
  k_chlog_m<<<dim3(2,16), dim3(256), 0, stream>>>(ftC, kvC, chl);
  k_chsm  <<<dim3(256),  dim3(256), 0, stream>>>(chl, chlb);
  k_chout_m<<<dim3(8,16), dim3(256), 0, stream>>>(chlb, kvT, c_t, ch, stats+128);

  // fused sa+ca 5x5 MFMA convs with LN-on-load (stats: sa=160, ca=192)
  {
    Segs3 SC;
    SC.s[0] = Seg{ sp, wbsa, nullptr, samid, stats+160, stats+96,  sng, snb, 64, 64, 1.f/65536.f };
    SC.s[1] = Seg{ ch, wbca, ca_b1,   camid, stats+192, stats+128, cng, cnb, 64, 64, 1.f/65536.f };
    SC.s[2] = SC.s[1];
    SC.b1 = 2; SC.b2 = 1000;   // cogs: sa 0-1, ca 2-3
    k_convX<2><<<dim3(16,16), dim3(256), 0, stream>>>(SC);
  }

  k_attnfinal<<<dim3(16,16), dim3(256), 0, stream>>>(samid, camid, stats+160, stats+192,
                                                     salng, salnb, calng, calnb,
                                                     sa_w2, ca_w2, ca_b2, attn_w,
                                                     ig, out_c, memo);

  // conv_o over mem (Cin=128)  (stats: o=224)
  {
    Segs3 O;
    O.s[0] = Seg{ memo, wbo, nullptr, bufo, stats+224, nullptr, nullptr, nullptr, 128, 64, 0.f };
    O.s[1] = O.s[0]; O.s[2] = O.s[0];
    O.b1 = 1000; O.b2 = 1000;  // cogs 0-1, single segment
    k_convX<2><<<dim3(8,16), dim3(256), 0, stream>>>(O);
  }

  k_final<<<dim3(16,16), dim3(256), 0, stream>>>(memo, w_last, bufo, osum, stats+224,
                                                 lnog, lnob, out_h);
}